// Round 1
// baseline (2726.562 us; speedup 1.0000x reference)
//
#include <hip/hip_runtime.h>
#include <hip/hip_bf16.h>
#include <math.h>

// Problem constants
constexpr int kB = 256, kS = 20, kE = 128, kH = 256;
constexpr int kTotalW = 2768;           // 432+16 + 2304+16
constexpr float kSlope = 1.0f / 5.5f;

// ---------------------------------------------------------------------------
// zero-fill (ws is poisoned 0xAA every call)
__global__ void zero_f32(float* __restrict__ p, int n) {
    for (int i = blockIdx.x * blockDim.x + threadIdx.x; i < n; i += gridDim.x * blockDim.x)
        p[i] = 0.f;
}

// ---------------------------------------------------------------------------
// xih[(s*B+b)*4H + j] = emb[q[b,s]] . w_ih[j,:] + b_ih[j] + b_hh[j]
// Tiled NT GEMM, M=5120 gathered rows, N=1024, K=128. grid (80,16), block 256.
__global__ __launch_bounds__(256) void xih_gemm(
    const int* __restrict__ questions, const float* __restrict__ emb,
    const float* __restrict__ w_ih, const float* __restrict__ b_ih,
    const float* __restrict__ b_hh, float* __restrict__ xih) {
    __shared__ float As[64][17];
    __shared__ float Bs[64][17];
    __shared__ int qs[64];
    const int m0 = blockIdx.x * 64, j0 = blockIdx.y * 64;
    const int tid = threadIdx.x, tx = tid % 16, ty = tid / 16;
    if (tid < 64) {
        int m = m0 + tid;
        int s = m / kB, b = m % kB;
        qs[tid] = questions[b * kS + s];
    }
    __syncthreads();
    float acc[4][4] = {};
    for (int k0 = 0; k0 < kE; k0 += 16) {
        for (int i = tid; i < 1024; i += 256) {
            int r = i / 16, c = i % 16;
            As[r][c] = emb[(size_t)qs[r] * kE + k0 + c];
        }
        for (int i = tid; i < 1024; i += 256) {
            int r = i / 16, c = i % 16;
            Bs[r][c] = w_ih[(size_t)(j0 + r) * kE + k0 + c];
        }
        __syncthreads();
#pragma unroll
        for (int kk = 0; kk < 16; ++kk) {
            float a[4], bl[4];
#pragma unroll
            for (int i = 0; i < 4; ++i) a[i] = As[ty * 4 + i][kk];
#pragma unroll
            for (int j = 0; j < 4; ++j) bl[j] = Bs[tx * 4 + j][kk];
#pragma unroll
            for (int i = 0; i < 4; ++i)
#pragma unroll
                for (int j = 0; j < 4; ++j) acc[i][j] += a[i] * bl[j];
        }
        __syncthreads();
    }
#pragma unroll
    for (int i = 0; i < 4; ++i)
#pragma unroll
        for (int j = 0; j < 4; ++j) {
            int m = m0 + ty * 4 + i, jj = j0 + tx * 4 + j;
            xih[(size_t)m * 1024 + jj] = acc[i][j] + b_ih[jj] + b_hh[jj];
        }
}

// ---------------------------------------------------------------------------
// One LSTM step: gates = xih_t + h_prev @ w_hh^T, then c/h update.
// grid (B/32, H/32) = (8,8), block 256. Each thread: 2b x 2j x 4 gates.
__global__ __launch_bounds__(256) void lstm_step(
    const float* __restrict__ xih_t,   // (B, 4H), already offset to step t
    const float* __restrict__ w_hh,    // (4H, H)
    const float* __restrict__ h_prev, const float* __restrict__ c_prev,
    float* __restrict__ h_new, float* __restrict__ c_new) {
    __shared__ float As[32][33];
    __shared__ float Ws[4][32][33];
    const int b0 = blockIdx.x * 32, j0 = blockIdx.y * 32;
    const int tid = threadIdx.x, tj = tid % 16, tb = tid / 16;
    float acc[4][2][2] = {};
    for (int k0 = 0; k0 < kH; k0 += 32) {
        for (int i = tid; i < 32 * 32; i += 256) {
            int r = i / 32, c = i % 32;
            As[r][c] = h_prev[(size_t)(b0 + r) * kH + k0 + c];
        }
        for (int i = tid; i < 4 * 32 * 32; i += 256) {
            int g = i / 1024, rem = i % 1024, r = rem / 32, c = rem % 32;
            Ws[g][r][c] = w_hh[(size_t)(g * kH + j0 + r) * kH + k0 + c];
        }
        __syncthreads();
#pragma unroll
        for (int kk = 0; kk < 32; ++kk) {
            float a0 = As[tb * 2 + 0][kk], a1 = As[tb * 2 + 1][kk];
#pragma unroll
            for (int g = 0; g < 4; ++g) {
                float w0 = Ws[g][tj * 2 + 0][kk], w1 = Ws[g][tj * 2 + 1][kk];
                acc[g][0][0] += a0 * w0; acc[g][0][1] += a0 * w1;
                acc[g][1][0] += a1 * w0; acc[g][1][1] += a1 * w1;
            }
        }
        __syncthreads();
    }
#pragma unroll
    for (int bb = 0; bb < 2; ++bb)
#pragma unroll
        for (int jj = 0; jj < 2; ++jj) {
            int b = b0 + tb * 2 + bb, j = j0 + tj * 2 + jj;
            float gi = acc[0][bb][jj] + xih_t[(size_t)b * 1024 + 0 * kH + j];
            float gf = acc[1][bb][jj] + xih_t[(size_t)b * 1024 + 1 * kH + j];
            float gg = acc[2][bb][jj] + xih_t[(size_t)b * 1024 + 2 * kH + j];
            float go = acc[3][bb][jj] + xih_t[(size_t)b * 1024 + 3 * kH + j];
            float i_ = 1.f / (1.f + expf(-gi));
            float f_ = 1.f / (1.f + expf(-gf));
            float g_ = tanhf(gg);
            float o_ = 1.f / (1.f + expf(-go));
            float c = f_ * c_prev[(size_t)b * kH + j] + i_ * g_;
            c_new[(size_t)b * kH + j] = c;
            h_new[(size_t)b * kH + j] = o_ * tanhf(c);
        }
}

// ---------------------------------------------------------------------------
// Generic NN GEMM: C = act(A(M,K) @ B(K,N) + bias). ACT: 0 none, 1 lrelu, 2 relu.
// 64x64 tile, Ktile 16, block 256, 4x4 per thread. M % 64 == 0, K % 16 == 0; N guarded.
template <int ACT>
__global__ __launch_bounds__(256) void gemm_nn(
    const float* __restrict__ A, const float* __restrict__ Bm,
    const float* __restrict__ bias, float* __restrict__ C,
    int M, int N, int K) {
    __shared__ float As[64][17];
    __shared__ float Bs[16][65];
    const int m0 = blockIdx.x * 64, n0 = blockIdx.y * 64;
    const int tid = threadIdx.x, tx = tid % 16, ty = tid / 16;
    float acc[4][4] = {};
    for (int k0 = 0; k0 < K; k0 += 16) {
        for (int i = tid; i < 1024; i += 256) {
            int r = i / 16, c = i % 16;
            As[r][c] = A[(size_t)(m0 + r) * K + k0 + c];
        }
        for (int i = tid; i < 1024; i += 256) {
            int r = i / 64, c = i % 64;
            int n = n0 + c;
            Bs[r][c] = (n < N) ? Bm[(size_t)(k0 + r) * N + n] : 0.f;
        }
        __syncthreads();
#pragma unroll
        for (int kk = 0; kk < 16; ++kk) {
            float a[4], bl[4];
#pragma unroll
            for (int i = 0; i < 4; ++i) a[i] = As[ty * 4 + i][kk];
#pragma unroll
            for (int j = 0; j < 4; ++j) bl[j] = Bs[kk][tx * 4 + j];
#pragma unroll
            for (int i = 0; i < 4; ++i)
#pragma unroll
                for (int j = 0; j < 4; ++j) acc[i][j] += a[i] * bl[j];
        }
        __syncthreads();
    }
#pragma unroll
    for (int i = 0; i < 4; ++i)
#pragma unroll
        for (int j = 0; j < 4; ++j) {
            int m = m0 + ty * 4 + i, n = n0 + tx * 4 + j;
            if (n < N) {
                float v = acc[i][j] + bias[n];
                if (ACT == 1) v = v > 0.f ? v : v * kSlope;
                if (ACT == 2) v = fmaxf(v, 0.f);
                C[(size_t)m * N + n] = v;
            }
        }
}

// ---------------------------------------------------------------------------
// Split-K GEMM (no bias/act): atomicAdd partials into Cacc. grid (M/64, N/64, splits).
__global__ __launch_bounds__(256) void gemm_nn_splitk(
    const float* __restrict__ A, const float* __restrict__ Bm,
    float* __restrict__ Cacc, int M, int N, int K, int Kchunk) {
    __shared__ float As[64][17];
    __shared__ float Bs[16][65];
    const int m0 = blockIdx.x * 64, n0 = blockIdx.y * 64;
    const int kbeg = blockIdx.z * Kchunk;
    const int tid = threadIdx.x, tx = tid % 16, ty = tid / 16;
    float acc[4][4] = {};
    for (int k0 = kbeg; k0 < kbeg + Kchunk; k0 += 16) {
        for (int i = tid; i < 1024; i += 256) {
            int r = i / 16, c = i % 16;
            As[r][c] = A[(size_t)(m0 + r) * K + k0 + c];
        }
        for (int i = tid; i < 1024; i += 256) {
            int r = i / 64, c = i % 64;
            Bs[r][c] = Bm[(size_t)(k0 + r) * N + n0 + c];
        }
        __syncthreads();
#pragma unroll
        for (int kk = 0; kk < 16; ++kk) {
            float a[4], bl[4];
#pragma unroll
            for (int i = 0; i < 4; ++i) a[i] = As[ty * 4 + i][kk];
#pragma unroll
            for (int j = 0; j < 4; ++j) bl[j] = Bs[kk][tx * 4 + j];
#pragma unroll
            for (int i = 0; i < 4; ++i)
#pragma unroll
                for (int j = 0; j < 4; ++j) acc[i][j] += a[i] * bl[j];
        }
        __syncthreads();
    }
#pragma unroll
    for (int i = 0; i < 4; ++i)
#pragma unroll
        for (int j = 0; j < 4; ++j) {
            int m = m0 + ty * 4 + i, n = n0 + tx * 4 + j;
            atomicAdd(&Cacc[(size_t)m * N + n], acc[i][j]);
        }
}

__global__ void bias_relu(const float* __restrict__ acc, const float* __restrict__ bias,
                          float* __restrict__ out, int M, int N) {
    int i = blockIdx.x * blockDim.x + threadIdx.x;
    if (i < M * N) {
        int n = i % N;
        out[i] = fmaxf(acc[i] + bias[n], 0.f);
    }
}

// ---------------------------------------------------------------------------
// Fused per-sample conv1(3->16) + conv2(16->16), 3x3, pad 1, NO activation between.
// Exact: conv2's zero-padding of conv1's output is reproduced by zeroed halo.
// grid (8, B) : 8 row-slabs of 8 rows. block 256.
__global__ __launch_bounds__(256) void conv_fused(
    const float* __restrict__ img,     // (B,3,64,64)
    const float* __restrict__ all_w,   // (B,2768)
    float* __restrict__ out) {         // (B,16,64,64)
    const int b = blockIdx.y;
    const int y0 = blockIdx.x * 8;
    __shared__ float in_s[3][12][66];
    __shared__ float mid_s[16][10][66];
    __shared__ float w1_s[448];    // 16*3*9 weights + 16 bias
    __shared__ float w2_s[2320];   // 16*16*9 weights + 16 bias
    const int tid = threadIdx.x;
    const float* wb = all_w + (size_t)b * kTotalW;
    for (int i = tid; i < 448; i += 256) w1_s[i] = wb[i];
    for (int i = tid; i < 2320; i += 256) w2_s[i] = wb[448 + i];
    // input rows y0-2 .. y0+9 with zeroed borders
    for (int i = tid; i < 3 * 12 * 66; i += 256) {
        int c = i / (12 * 66), rem = i % (12 * 66), r = rem / 66, x = rem % 66;
        int gy = y0 - 2 + r, gx = x - 1;
        float v = 0.f;
        if (gy >= 0 && gy < 64 && gx >= 0 && gx < 64)
            v = img[(((size_t)b * 3 + c) * 64 + gy) * 64 + gx];
        in_s[c][r][x] = v;
    }
    __syncthreads();
    // conv1 into mid rows (global y0-1 .. y0+8); rows outside [0,64) are conv2's zero pad
    for (int i = tid; i < 16 * 10 * 64; i += 256) {
        int o = i / 640, rem = i % 640, r = rem / 64, x = rem % 64;
        int gy = y0 - 1 + r;
        float acc = 0.f;
        if (gy >= 0 && gy < 64) {
            acc = w1_s[432 + o];
#pragma unroll
            for (int c = 0; c < 3; ++c)
#pragma unroll
                for (int dy = 0; dy < 3; ++dy)
#pragma unroll
                    for (int dx = 0; dx < 3; ++dx)
                        acc += in_s[c][r + dy][x + dx] * w1_s[(o * 3 + c) * 9 + dy * 3 + dx];
        }
        mid_s[o][r][x + 1] = acc;
    }
    if (tid < 160) {
        int o = tid / 10, r = tid % 10;
        mid_s[o][r][0] = 0.f;
        mid_s[o][r][65] = 0.f;
    }
    __syncthreads();
    // conv2: out rows y0 .. y0+7
    const int x = tid & 63, ry = tid >> 6;
#pragma unroll
    for (int rr = 0; rr < 2; ++rr) {
        int r = ry + rr * 4;  // 0..7; mid local rows r..r+2
        float acc[16];
#pragma unroll
        for (int o = 0; o < 16; ++o) acc[o] = w2_s[2304 + o];
        for (int c = 0; c < 16; ++c) {
#pragma unroll
            for (int dy = 0; dy < 3; ++dy) {
                float v0 = mid_s[c][r + dy][x + 0];
                float v1 = mid_s[c][r + dy][x + 1];
                float v2 = mid_s[c][r + dy][x + 2];
#pragma unroll
                for (int o = 0; o < 16; ++o) {
                    const float* w = &w2_s[(o * 16 + c) * 9 + dy * 3];
                    acc[o] += v0 * w[0] + v1 * w[1] + v2 * w[2];
                }
            }
        }
#pragma unroll
        for (int o = 0; o < 16; ++o)
            out[(((size_t)b * 16 + o) * 64 + (y0 + r)) * 64 + x] = acc[o];
    }
}

// ---------------------------------------------------------------------------
// Fused lin2+lin3: out(256,2). grid B, block 64.
__global__ __launch_bounds__(64) void lin23(
    const float* __restrict__ l1out,  // (256,512)
    const float* __restrict__ lw2, const float* __restrict__ lb2,
    const float* __restrict__ lw3, const float* __restrict__ lb3,
    float* __restrict__ out) {
    const int b = blockIdx.x, j = threadIdx.x;
    __shared__ float row[512];
    __shared__ float s[64];
    for (int i = j; i < 512; i += 64) row[i] = l1out[(size_t)b * 512 + i];
    __syncthreads();
    float acc = lb2[j];
    for (int k = 0; k < 512; ++k) acc += row[k] * lw2[(size_t)k * 64 + j];
    s[j] = fmaxf(acc, 0.f);
    __syncthreads();
    if (j < 2) {
        float o = lb3[j];
        for (int k = 0; k < 64; ++k) o += s[k] * lw3[(size_t)k * 2 + j];
        out[(size_t)b * 2 + j] = o;
    }
}

// ---------------------------------------------------------------------------
extern "C" void kernel_launch(void* const* d_in, const int* in_sizes, int n_in,
                              void* d_out, int out_size, void* d_ws, size_t ws_size,
                              hipStream_t stream) {
    const int* questions = (const int*)d_in[0];
    const float* images  = (const float*)d_in[1];
    const float* emb     = (const float*)d_in[2];
    const float* w_ih    = (const float*)d_in[3];
    const float* w_hh    = (const float*)d_in[4];
    const float* b_ih    = (const float*)d_in[5];
    const float* b_hh    = (const float*)d_in[6];
    const float* hw1     = (const float*)d_in[7];
    const float* hb1     = (const float*)d_in[8];
    const float* hw2     = (const float*)d_in[9];
    const float* hb2     = (const float*)d_in[10];
    const float* hw3     = (const float*)d_in[11];
    const float* hb3     = (const float*)d_in[12];
    const float* lw1     = (const float*)d_in[13];
    const float* lb1     = (const float*)d_in[14];
    const float* lw2     = (const float*)d_in[15];
    const float* lb2     = (const float*)d_in[16];
    const float* lw3     = (const float*)d_in[17];
    const float* lb3     = (const float*)d_in[18];
    float* out = (float*)d_out;

    char* ws = (char*)d_ws;
    size_t off = 0;
    auto alloc = [&](size_t nbytes) -> void* {
        void* p = (void*)(ws + off);
        off += (nbytes + 255) & ~(size_t)255;
        return p;
    };
    // 64MB region shared: xih (20MB, dead after LSTM) then conv2 output (64MB)
    float* big   = (float*)alloc(64ull << 20);
    float* hc0   = (float*)alloc(2 * kB * kH * sizeof(float));  // h0|c0 adjacent
    float* hc1   = (float*)alloc(2 * kB * kH * sizeof(float));
    float* h1    = (float*)alloc((size_t)kB * 1024 * sizeof(float));
    float* h2    = (float*)alloc((size_t)kB * 4096 * sizeof(float));
    float* allw  = (float*)alloc((size_t)kB * kTotalW * sizeof(float));
    float* acc1  = (float*)alloc((size_t)kB * 512 * sizeof(float));
    float* l1out = (float*)alloc((size_t)kB * 512 * sizeof(float));

    float* xih = big;
    float* c2out = big;
    float* hbuf[2] = {hc0, hc1};
    float* cbuf[2] = {hc0 + kB * kH, hc1 + kB * kH};

    zero_f32<<<256, 256, 0, stream>>>(hc0, 2 * kB * kH);     // h0=c0=0
    zero_f32<<<256, 256, 0, stream>>>(acc1, kB * 512);       // split-K accumulator

    // 1) xih = emb[q] @ w_ih^T + b_ih + b_hh, laid out (S,B,4H)
    xih_gemm<<<dim3(80, 16), 256, 0, stream>>>(questions, emb, w_ih, b_ih, b_hh, xih);

    // 2) 20 LSTM steps (ping-pong h/c)
    for (int t = 0; t < kS; ++t) {
        lstm_step<<<dim3(8, 8), 256, 0, stream>>>(
            xih + (size_t)t * kB * 1024, w_hh,
            hbuf[t & 1], cbuf[t & 1], hbuf[(t + 1) & 1], cbuf[(t + 1) & 1]);
    }
    const float* hfin = hbuf[0];  // t=19 writes buffer 0

    // 3) hyper-MLP
    gemm_nn<1><<<dim3(4, 16), 256, 0, stream>>>(hfin, hw1, hb1, h1, 256, 1024, 256);
    gemm_nn<1><<<dim3(4, 64), 256, 0, stream>>>(h1, hw2, hb2, h2, 256, 4096, 1024);
    gemm_nn<0><<<dim3(4, 44), 256, 0, stream>>>(h2, hw3, hb3, allw, 256, 2768, 4096);

    // 4) fused conv1+conv2 with per-sample generated weights
    conv_fused<<<dim3(8, 256), 256, 0, stream>>>(images, allw, c2out);

    // 5) lin1: 256x512, K=65536, split-K 32
    gemm_nn_splitk<<<dim3(4, 8, 32), 256, 0, stream>>>(c2out, lw1, acc1, 256, 512, 65536, 2048);
    bias_relu<<<512, 256, 0, stream>>>(acc1, lb1, l1out, 256, 512);

    // 6) lin2+lin3 fused -> out (256,2)
    lin23<<<256, 64, 0, stream>>>(l1out, lw2, lb2, lw3, lb3, out);
}

// Round 2
// 1795.635 us; speedup vs baseline: 1.5184x; 1.5184x over previous
//
#include <hip/hip_runtime.h>
#include <hip/hip_bf16.h>
#include <math.h>

// Problem constants
constexpr int kB = 256, kS = 20, kE = 128, kH = 256;
constexpr int kTotalW = 2768;           // 432+16 + 2304+16
constexpr float kSlope = 1.0f / 5.5f;

typedef __bf16 bf16x8 __attribute__((ext_vector_type(8)));
typedef float  floatx4 __attribute__((ext_vector_type(4)));

// ---------------------------------------------------------------------------
// zero-fill (ws is poisoned 0xAA every call)
__global__ void zero_f32(float* __restrict__ p, int n) {
    for (int i = blockIdx.x * blockDim.x + threadIdx.x; i < n; i += gridDim.x * blockDim.x)
        p[i] = 0.f;
}

// rowmajor fp32 -> bf16 (RNE)
__global__ void cvt_bf16(const float* __restrict__ in, __bf16* __restrict__ out, int n) {
    for (int i = blockIdx.x * blockDim.x + threadIdx.x; i < n; i += gridDim.x * blockDim.x)
        out[i] = (__bf16)in[i];
}

// W (K x N fp32, row-major) -> Wt (N x K bf16, row-major). grid (K/32, ceil(N/32)), block 256.
__global__ __launch_bounds__(256) void transpose_cvt(
    const float* __restrict__ W, __bf16* __restrict__ Wt, int K, int N) {
    __shared__ float t[32][33];
    const int k0 = blockIdx.x * 32, n0 = blockIdx.y * 32;
    const int tx = threadIdx.x & 31, ty = threadIdx.x >> 5;   // 32 x 8
#pragma unroll
    for (int j = 0; j < 32; j += 8) {
        int n = n0 + tx, k = k0 + ty + j;
        t[ty + j][tx] = (n < N) ? W[(size_t)k * N + n] : 0.f;
    }
    __syncthreads();
#pragma unroll
    for (int j = 0; j < 32; j += 8) {
        int n = n0 + ty + j, k = k0 + tx;
        if (n < N) Wt[(size_t)n * K + k] = (__bf16)t[tx][ty + j];
    }
}

// ---------------------------------------------------------------------------
// bf16 MFMA split-K GEMM: Cacc(M,N fp32, pre-zeroed) += A(MxK bf16) @ Bt(NxK bf16)^T
// 64x64 tile, BK=64, 4 waves x (16 rows x 64 cols), grid (M/64, ceil(N/64), splits).
// Fragment layouts (verified, learn_hip m89/m91): A/B [outer=lane&15][k=(lane>>4)*8+j],
// C/D col=lane&15, row=(lane>>4)*4+reg. LDS rows padded to 72 bf16 -> frag reads 2-way (free).
__global__ __launch_bounds__(256) void mfma_splitk(
    const __bf16* __restrict__ A, const __bf16* __restrict__ Bt,
    float* __restrict__ Cacc, int M, int N, int K, int Kchunk) {
    __shared__ __bf16 As[64][72];
    __shared__ __bf16 Bs[64][72];
    const int m0 = blockIdx.x * 64, n0 = blockIdx.y * 64;
    const int kbeg = blockIdx.z * Kchunk, kend = kbeg + Kchunk;
    const int tid = threadIdx.x, lane = tid & 63, wave = tid >> 6;
    floatx4 acc[4] = {};
    for (int k0 = kbeg; k0 < kend; k0 += 64) {
        for (int i = tid; i < 512; i += 256) {          // A tile: 64 rows x 64 k
            int r = i >> 3, seg = i & 7;
            uint4 v = *(const uint4*)(A + (size_t)(m0 + r) * K + k0 + seg * 8);
            *(uint4*)(&As[r][seg * 8]) = v;
        }
        for (int i = tid; i < 512; i += 256) {          // B^T tile: 64 n-rows x 64 k
            int r = i >> 3, seg = i & 7;
            uint4 v = make_uint4(0u, 0u, 0u, 0u);
            if (n0 + r < N) v = *(const uint4*)(Bt + (size_t)(n0 + r) * K + k0 + seg * 8);
            *(uint4*)(&Bs[r][seg * 8]) = v;
        }
        __syncthreads();
#pragma unroll
        for (int ks = 0; ks < 2; ++ks) {
            bf16x8 af = *(const bf16x8*)(&As[wave * 16 + (lane & 15)][ks * 32 + (lane >> 4) * 8]);
#pragma unroll
            for (int nb = 0; nb < 4; ++nb) {
                bf16x8 bfr = *(const bf16x8*)(&Bs[nb * 16 + (lane & 15)][ks * 32 + (lane >> 4) * 8]);
                acc[nb] = __builtin_amdgcn_mfma_f32_16x16x32_bf16(af, bfr, acc[nb], 0, 0, 0);
            }
        }
        __syncthreads();
    }
    const int col = lane & 15, rq = (lane >> 4) * 4;
#pragma unroll
    for (int nb = 0; nb < 4; ++nb)
#pragma unroll
        for (int r = 0; r < 4; ++r) {
            int m = m0 + wave * 16 + rq + r, n = n0 + nb * 16 + col;
            if (n < N) atomicAdd(&Cacc[(size_t)m * N + n], acc[nb][r]);
        }
}

// epilogues: bias + leaky-relu -> bf16 (feeds next MFMA GEMM) / bias only -> fp32
__global__ void ep_lrelu_bf16(const float* __restrict__ acc, const float* __restrict__ bias,
                              __bf16* __restrict__ out, int M, int N) {
    int i = blockIdx.x * blockDim.x + threadIdx.x;
    if (i < M * N) {
        float v = acc[i] + bias[i % N];
        out[i] = (__bf16)(v > 0.f ? v : v * kSlope);
    }
}
__global__ void ep_bias_f32(const float* __restrict__ acc, const float* __restrict__ bias,
                            float* __restrict__ out, int M, int N) {
    int i = blockIdx.x * blockDim.x + threadIdx.x;
    if (i < M * N) out[i] = acc[i] + bias[i % N];
}

// ---------------------------------------------------------------------------
// xih[(s*B+b)*4H + j] = emb[q[b,s]] . w_ih[j,:] + b_ih[j] + b_hh[j]
__global__ __launch_bounds__(256) void xih_gemm(
    const int* __restrict__ questions, const float* __restrict__ emb,
    const float* __restrict__ w_ih, const float* __restrict__ b_ih,
    const float* __restrict__ b_hh, float* __restrict__ xih) {
    __shared__ float As[64][17];
    __shared__ float Bs[64][17];
    __shared__ int qs[64];
    const int m0 = blockIdx.x * 64, j0 = blockIdx.y * 64;
    const int tid = threadIdx.x, tx = tid % 16, ty = tid / 16;
    if (tid < 64) {
        int m = m0 + tid;
        int s = m / kB, b = m % kB;
        qs[tid] = questions[b * kS + s];
    }
    __syncthreads();
    float acc[4][4] = {};
    for (int k0 = 0; k0 < kE; k0 += 16) {
        for (int i = tid; i < 1024; i += 256) {
            int r = i / 16, c = i % 16;
            As[r][c] = emb[(size_t)qs[r] * kE + k0 + c];
        }
        for (int i = tid; i < 1024; i += 256) {
            int r = i / 16, c = i % 16;
            Bs[r][c] = w_ih[(size_t)(j0 + r) * kE + k0 + c];
        }
        __syncthreads();
#pragma unroll
        for (int kk = 0; kk < 16; ++kk) {
            float a[4], bl[4];
#pragma unroll
            for (int i = 0; i < 4; ++i) a[i] = As[ty * 4 + i][kk];
#pragma unroll
            for (int j = 0; j < 4; ++j) bl[j] = Bs[tx * 4 + j][kk];
#pragma unroll
            for (int i = 0; i < 4; ++i)
#pragma unroll
                for (int j = 0; j < 4; ++j) acc[i][j] += a[i] * bl[j];
        }
        __syncthreads();
    }
#pragma unroll
    for (int i = 0; i < 4; ++i)
#pragma unroll
        for (int j = 0; j < 4; ++j) {
            int m = m0 + ty * 4 + i, jj = j0 + tx * 4 + j;
            xih[(size_t)m * 1024 + jj] = acc[i][j] + b_ih[jj] + b_hh[jj];
        }
}

// ---------------------------------------------------------------------------
// One LSTM step: gates = xih_t + h_prev @ w_hh^T, then c/h update.
__global__ __launch_bounds__(256) void lstm_step(
    const float* __restrict__ xih_t, const float* __restrict__ w_hh,
    const float* __restrict__ h_prev, const float* __restrict__ c_prev,
    float* __restrict__ h_new, float* __restrict__ c_new) {
    __shared__ float As[32][33];
    __shared__ float Ws[4][32][33];
    const int b0 = blockIdx.x * 32, j0 = blockIdx.y * 32;
    const int tid = threadIdx.x, tj = tid % 16, tb = tid / 16;
    float acc[4][2][2] = {};
    for (int k0 = 0; k0 < kH; k0 += 32) {
        for (int i = tid; i < 32 * 32; i += 256) {
            int r = i / 32, c = i % 32;
            As[r][c] = h_prev[(size_t)(b0 + r) * kH + k0 + c];
        }
        for (int i = tid; i < 4 * 32 * 32; i += 256) {
            int g = i / 1024, rem = i % 1024, r = rem / 32, c = rem % 32;
            Ws[g][r][c] = w_hh[(size_t)(g * kH + j0 + r) * kH + k0 + c];
        }
        __syncthreads();
#pragma unroll
        for (int kk = 0; kk < 32; ++kk) {
            float a0 = As[tb * 2 + 0][kk], a1 = As[tb * 2 + 1][kk];
#pragma unroll
            for (int g = 0; g < 4; ++g) {
                float w0 = Ws[g][tj * 2 + 0][kk], w1 = Ws[g][tj * 2 + 1][kk];
                acc[g][0][0] += a0 * w0; acc[g][0][1] += a0 * w1;
                acc[g][1][0] += a1 * w0; acc[g][1][1] += a1 * w1;
            }
        }
        __syncthreads();
    }
#pragma unroll
    for (int bb = 0; bb < 2; ++bb)
#pragma unroll
        for (int jj = 0; jj < 2; ++jj) {
            int b = b0 + tb * 2 + bb, j = j0 + tj * 2 + jj;
            float gi = acc[0][bb][jj] + xih_t[(size_t)b * 1024 + 0 * kH + j];
            float gf = acc[1][bb][jj] + xih_t[(size_t)b * 1024 + 1 * kH + j];
            float gg = acc[2][bb][jj] + xih_t[(size_t)b * 1024 + 2 * kH + j];
            float go = acc[3][bb][jj] + xih_t[(size_t)b * 1024 + 3 * kH + j];
            float i_ = 1.f / (1.f + expf(-gi));
            float f_ = 1.f / (1.f + expf(-gf));
            float g_ = tanhf(gg);
            float o_ = 1.f / (1.f + expf(-go));
            float c = f_ * c_prev[(size_t)b * kH + j] + i_ * g_;
            c_new[(size_t)b * kH + j] = c;
            h_new[(size_t)b * kH + j] = o_ * tanhf(c);
        }
}

// ---------------------------------------------------------------------------
// Split-K fp32 GEMM (lin1): atomicAdd partials into Cacc. grid (M/64, N/64, splits).
__global__ __launch_bounds__(256) void gemm_nn_splitk(
    const float* __restrict__ A, const float* __restrict__ Bm,
    float* __restrict__ Cacc, int M, int N, int K, int Kchunk) {
    __shared__ float As[64][17];
    __shared__ float Bs[16][65];
    const int m0 = blockIdx.x * 64, n0 = blockIdx.y * 64;
    const int kbeg = blockIdx.z * Kchunk;
    const int tid = threadIdx.x, tx = tid % 16, ty = tid / 16;
    float acc[4][4] = {};
    for (int k0 = kbeg; k0 < kbeg + Kchunk; k0 += 16) {
        for (int i = tid; i < 1024; i += 256) {
            int r = i / 16, c = i % 16;
            As[r][c] = A[(size_t)(m0 + r) * K + k0 + c];
        }
        for (int i = tid; i < 1024; i += 256) {
            int r = i / 64, c = i % 64;
            Bs[r][c] = Bm[(size_t)(k0 + r) * N + n0 + c];
        }
        __syncthreads();
#pragma unroll
        for (int kk = 0; kk < 16; ++kk) {
            float a[4], bl[4];
#pragma unroll
            for (int i = 0; i < 4; ++i) a[i] = As[ty * 4 + i][kk];
#pragma unroll
            for (int j = 0; j < 4; ++j) bl[j] = Bs[kk][tx * 4 + j];
#pragma unroll
            for (int i = 0; i < 4; ++i)
#pragma unroll
                for (int j = 0; j < 4; ++j) acc[i][j] += a[i] * bl[j];
        }
        __syncthreads();
    }
#pragma unroll
    for (int i = 0; i < 4; ++i)
#pragma unroll
        for (int j = 0; j < 4; ++j) {
            int m = m0 + ty * 4 + i, n = n0 + tx * 4 + j;
            atomicAdd(&Cacc[(size_t)m * N + n], acc[i][j]);
        }
}

__global__ void bias_relu(const float* __restrict__ acc, const float* __restrict__ bias,
                          float* __restrict__ out, int M, int N) {
    int i = blockIdx.x * blockDim.x + threadIdx.x;
    if (i < M * N) {
        int n = i % N;
        out[i] = fmaxf(acc[i] + bias[n], 0.f);
    }
}

// ---------------------------------------------------------------------------
// Fused per-sample conv1(3->16) + conv2(16->16), 3x3, pad 1, NO activation between.
__global__ __launch_bounds__(256) void conv_fused(
    const float* __restrict__ img, const float* __restrict__ all_w,
    float* __restrict__ out) {
    const int b = blockIdx.y;
    const int y0 = blockIdx.x * 8;
    __shared__ float in_s[3][12][66];
    __shared__ float mid_s[16][10][66];
    __shared__ float w1_s[448];
    __shared__ float w2_s[2320];
    const int tid = threadIdx.x;
    const float* wb = all_w + (size_t)b * kTotalW;
    for (int i = tid; i < 448; i += 256) w1_s[i] = wb[i];
    for (int i = tid; i < 2320; i += 256) w2_s[i] = wb[448 + i];
    for (int i = tid; i < 3 * 12 * 66; i += 256) {
        int c = i / (12 * 66), rem = i % (12 * 66), r = rem / 66, x = rem % 66;
        int gy = y0 - 2 + r, gx = x - 1;
        float v = 0.f;
        if (gy >= 0 && gy < 64 && gx >= 0 && gx < 64)
            v = img[(((size_t)b * 3 + c) * 64 + gy) * 64 + gx];
        in_s[c][r][x] = v;
    }
    __syncthreads();
    for (int i = tid; i < 16 * 10 * 64; i += 256) {
        int o = i / 640, rem = i % 640, r = rem / 64, x = rem % 64;
        int gy = y0 - 1 + r;
        float acc = 0.f;
        if (gy >= 0 && gy < 64) {
            acc = w1_s[432 + o];
#pragma unroll
            for (int c = 0; c < 3; ++c)
#pragma unroll
                for (int dy = 0; dy < 3; ++dy)
#pragma unroll
                    for (int dx = 0; dx < 3; ++dx)
                        acc += in_s[c][r + dy][x + dx] * w1_s[(o * 3 + c) * 9 + dy * 3 + dx];
        }
        mid_s[o][r][x + 1] = acc;
    }
    if (tid < 160) {
        int o = tid / 10, r = tid % 10;
        mid_s[o][r][0] = 0.f;
        mid_s[o][r][65] = 0.f;
    }
    __syncthreads();
    const int x = tid & 63, ry = tid >> 6;
#pragma unroll
    for (int rr = 0; rr < 2; ++rr) {
        int r = ry + rr * 4;
        float acc[16];
#pragma unroll
        for (int o = 0; o < 16; ++o) acc[o] = w2_s[2304 + o];
        for (int c = 0; c < 16; ++c) {
#pragma unroll
            for (int dy = 0; dy < 3; ++dy) {
                float v0 = mid_s[c][r + dy][x + 0];
                float v1 = mid_s[c][r + dy][x + 1];
                float v2 = mid_s[c][r + dy][x + 2];
#pragma unroll
                for (int o = 0; o < 16; ++o) {
                    const float* w = &w2_s[(o * 16 + c) * 9 + dy * 3];
                    acc[o] += v0 * w[0] + v1 * w[1] + v2 * w[2];
                }
            }
        }
#pragma unroll
        for (int o = 0; o < 16; ++o)
            out[(((size_t)b * 16 + o) * 64 + (y0 + r)) * 64 + x] = acc[o];
    }
}

// ---------------------------------------------------------------------------
// Fused lin2+lin3: out(256,2). grid B, block 64.
__global__ __launch_bounds__(64) void lin23(
    const float* __restrict__ l1out,
    const float* __restrict__ lw2, const float* __restrict__ lb2,
    const float* __restrict__ lw3, const float* __restrict__ lb3,
    float* __restrict__ out) {
    const int b = blockIdx.x, j = threadIdx.x;
    __shared__ float row[512];
    __shared__ float s[64];
    for (int i = j; i < 512; i += 64) row[i] = l1out[(size_t)b * 512 + i];
    __syncthreads();
    float acc = lb2[j];
    for (int k = 0; k < 512; ++k) acc += row[k] * lw2[(size_t)k * 64 + j];
    s[j] = fmaxf(acc, 0.f);
    __syncthreads();
    if (j < 2) {
        float o = lb3[j];
        for (int k = 0; k < 64; ++k) o += s[k] * lw3[(size_t)k * 2 + j];
        out[(size_t)b * 2 + j] = o;
    }
}

// ---------------------------------------------------------------------------
extern "C" void kernel_launch(void* const* d_in, const int* in_sizes, int n_in,
                              void* d_out, int out_size, void* d_ws, size_t ws_size,
                              hipStream_t stream) {
    const int* questions = (const int*)d_in[0];
    const float* images  = (const float*)d_in[1];
    const float* emb     = (const float*)d_in[2];
    const float* w_ih    = (const float*)d_in[3];
    const float* w_hh    = (const float*)d_in[4];
    const float* b_ih    = (const float*)d_in[5];
    const float* b_hh    = (const float*)d_in[6];
    const float* hw1     = (const float*)d_in[7];
    const float* hb1     = (const float*)d_in[8];
    const float* hw2     = (const float*)d_in[9];
    const float* hb2     = (const float*)d_in[10];
    const float* hw3     = (const float*)d_in[11];
    const float* hb3     = (const float*)d_in[12];
    const float* lw1     = (const float*)d_in[13];
    const float* lb1     = (const float*)d_in[14];
    const float* lw2     = (const float*)d_in[15];
    const float* lb2     = (const float*)d_in[16];
    const float* lw3     = (const float*)d_in[17];
    const float* lb3     = (const float*)d_in[18];
    float* out = (float*)d_out;

    char* ws = (char*)d_ws;
    size_t off = 0;
    auto alloc = [&](size_t nbytes) -> void* {
        void* p = (void*)(ws + off);
        off += (nbytes + 255) & ~(size_t)255;
        return p;
    };
    // big (64MB): [0..20MB) xih (dead after LSTM) | [24MB..46.7MB) w3t bf16 (dead after hw3 GEMM)
    // then the whole 64MB is conv output. All uses strictly ordered on one stream.
    float*  big  = (float*)alloc(64ull << 20);
    float*  hc0  = (float*)alloc(2 * kB * kH * sizeof(float));
    float*  hc1  = (float*)alloc(2 * kB * kH * sizeof(float));
    __bf16* w1t  = (__bf16*)alloc((size_t)1024 * 256 * 2);     // hw1^T bf16 (N=1024 x K=256)
    __bf16* w2t  = (__bf16*)alloc((size_t)4096 * 1024 * 2);    // hw2^T bf16
    __bf16* h0b  = (__bf16*)alloc((size_t)kB * kH * 2);        // task_codes bf16
    __bf16* h1b  = (__bf16*)alloc((size_t)kB * 1024 * 2);
    __bf16* h2b  = (__bf16*)alloc((size_t)kB * 4096 * 2);
    // contiguous fp32 accumulators (zeroed in one kernel): hw1 | hw2 | hw3 | lin1
    float*  accz = (float*)alloc((size_t)kB * (1024 + 4096 + 2768 + 512) * sizeof(float));
    float*  accA = accz;
    float*  accB = accA + (size_t)kB * 1024;
    float*  accC = accB + (size_t)kB * 4096;
    float*  acc1 = accC + (size_t)kB * 2768;
    float*  allw = (float*)alloc((size_t)kB * kTotalW * sizeof(float));
    float*  l1out= (float*)alloc((size_t)kB * 512 * sizeof(float));

    float* xih = big;
    float* c2out = big;
    __bf16* w3t = (__bf16*)((char*)big + (24ull << 20));       // 2768 x 4096 bf16 = 22.7MB
    float* hbuf[2] = {hc0, hc1};
    float* cbuf[2] = {hc0 + kB * kH, hc1 + kB * kH};

    const int nACC = kB * (1024 + 4096 + 2768 + 512);
    zero_f32<<<512, 256, 0, stream>>>(accz, nACC);
    zero_f32<<<256, 256, 0, stream>>>(hc0, 2 * kB * kH);       // h0=c0=0

    // weight transposes+converts (independent of LSTM; w3t region disjoint from xih)
    transpose_cvt<<<dim3(8, 32),   256, 0, stream>>>(hw1, w1t, 256, 1024);
    transpose_cvt<<<dim3(32, 128), 256, 0, stream>>>(hw2, w2t, 1024, 4096);
    transpose_cvt<<<dim3(128, 87), 256, 0, stream>>>(hw3, w3t, 4096, 2768);

    // 1) xih = emb[q] @ w_ih^T + b_ih + b_hh, laid out (S,B,4H)
    xih_gemm<<<dim3(80, 16), 256, 0, stream>>>(questions, emb, w_ih, b_ih, b_hh, xih);

    // 2) 20 LSTM steps (ping-pong h/c)
    for (int t = 0; t < kS; ++t) {
        lstm_step<<<dim3(8, 8), 256, 0, stream>>>(
            xih + (size_t)t * kB * 1024, w_hh,
            hbuf[t & 1], cbuf[t & 1], hbuf[(t + 1) & 1], cbuf[(t + 1) & 1]);
    }
    const float* hfin = hbuf[0];  // t=19 writes buffer 0
    cvt_bf16<<<64, 256, 0, stream>>>(hfin, h0b, kB * kH);

    // 3) hyper-MLP via bf16 MFMA split-K GEMMs
    mfma_splitk<<<dim3(4, 16, 4), 256, 0, stream>>>(h0b, w1t, accA, 256, 1024, 256, 64);
    ep_lrelu_bf16<<<1024, 256, 0, stream>>>(accA, hb1, h1b, 256, 1024);
    mfma_splitk<<<dim3(4, 64, 4), 256, 0, stream>>>(h1b, w2t, accB, 256, 4096, 1024, 256);
    ep_lrelu_bf16<<<4096, 256, 0, stream>>>(accB, hb2, h2b, 256, 4096);
    mfma_splitk<<<dim3(4, 44, 8), 256, 0, stream>>>(h2b, w3t, accC, 256, 2768, 4096, 512);
    ep_bias_f32<<<2769, 256, 0, stream>>>(accC, hb3, allw, 256, 2768);

    // 4) fused conv1+conv2 with per-sample generated weights
    conv_fused<<<dim3(8, 256), 256, 0, stream>>>(images, allw, c2out);

    // 5) lin1: 256x512, K=65536, split-K 32
    gemm_nn_splitk<<<dim3(4, 8, 32), 256, 0, stream>>>(c2out, lw1, acc1, 256, 512, 65536, 2048);
    bias_relu<<<512, 256, 0, stream>>>(acc1, lb1, l1out, 256, 512);

    // 6) lin2+lin3 fused -> out (256,2)
    lin23<<<256, 64, 0, stream>>>(l1out, lw2, lb2, lw3, lb3, out);
}

// Round 3
// 1416.150 us; speedup vs baseline: 1.9253x; 1.2680x over previous
//
#include <hip/hip_runtime.h>
#include <hip/hip_bf16.h>
#include <math.h>

// Problem constants
constexpr int kB = 256, kS = 20, kE = 128, kH = 256;
constexpr int kTotalW = 2768;           // 432+16 + 2304+16
constexpr float kSlope = 1.0f / 5.5f;

typedef __bf16 bf16x8 __attribute__((ext_vector_type(8)));
typedef float  floatx4 __attribute__((ext_vector_type(4)));

// ---------------------------------------------------------------------------
// zero-fill (ws is poisoned 0xAA every call)
__global__ void zero_f32(float* __restrict__ p, int n) {
    for (int i = blockIdx.x * blockDim.x + threadIdx.x; i < n; i += gridDim.x * blockDim.x)
        p[i] = 0.f;
}

// rowmajor fp32 -> bf16 (RNE)
__global__ void cvt_bf16(const float* __restrict__ in, __bf16* __restrict__ out, int n) {
    for (int i = blockIdx.x * blockDim.x + threadIdx.x; i < n; i += gridDim.x * blockDim.x)
        out[i] = (__bf16)in[i];
}

// W (K x N fp32, row-major) -> Wt (N x K bf16, row-major). grid (K/32, ceil(N/32)), block 256.
__global__ __launch_bounds__(256) void transpose_cvt(
    const float* __restrict__ W, __bf16* __restrict__ Wt, int K, int N) {
    __shared__ float t[32][33];
    const int k0 = blockIdx.x * 32, n0 = blockIdx.y * 32;
    const int tx = threadIdx.x & 31, ty = threadIdx.x >> 5;   // 32 x 8
#pragma unroll
    for (int j = 0; j < 32; j += 8) {
        int n = n0 + tx, k = k0 + ty + j;
        t[ty + j][tx] = (n < N) ? W[(size_t)k * N + n] : 0.f;
    }
    __syncthreads();
#pragma unroll
    for (int j = 0; j < 32; j += 8) {
        int n = n0 + ty + j, k = k0 + tx;
        if (n < N) Wt[(size_t)n * K + k] = (__bf16)t[tx][ty + j];
    }
}

// ---------------------------------------------------------------------------
// bf16 MFMA split-K GEMM: Cacc(M,N fp32, pre-zeroed) += A(MxK bf16) @ Bt(NxK bf16)^T
// 64x64 tile, BK=64, 4 waves x (16 rows x 64 cols), grid (M/64, ceil(N/64), splits).
// Fragment layouts (verified, learn_hip m89/m91): A/B [outer=lane&15][k=(lane>>4)*8+j],
// C/D col=lane&15, row=(lane>>4)*4+reg. LDS rows padded to 72 bf16 -> frag reads 2-way (free).
__global__ __launch_bounds__(256) void mfma_splitk(
    const __bf16* __restrict__ A, const __bf16* __restrict__ Bt,
    float* __restrict__ Cacc, int M, int N, int K, int Kchunk) {
    __shared__ __bf16 As[64][72];
    __shared__ __bf16 Bs[64][72];
    const int m0 = blockIdx.x * 64, n0 = blockIdx.y * 64;
    const int kbeg = blockIdx.z * Kchunk, kend = kbeg + Kchunk;
    const int tid = threadIdx.x, lane = tid & 63, wave = tid >> 6;
    floatx4 acc[4] = {};
    for (int k0 = kbeg; k0 < kend; k0 += 64) {
        for (int i = tid; i < 512; i += 256) {          // A tile: 64 rows x 64 k
            int r = i >> 3, seg = i & 7;
            uint4 v = *(const uint4*)(A + (size_t)(m0 + r) * K + k0 + seg * 8);
            *(uint4*)(&As[r][seg * 8]) = v;
        }
        for (int i = tid; i < 512; i += 256) {          // B^T tile: 64 n-rows x 64 k
            int r = i >> 3, seg = i & 7;
            uint4 v = make_uint4(0u, 0u, 0u, 0u);
            if (n0 + r < N) v = *(const uint4*)(Bt + (size_t)(n0 + r) * K + k0 + seg * 8);
            *(uint4*)(&Bs[r][seg * 8]) = v;
        }
        __syncthreads();
#pragma unroll
        for (int ks = 0; ks < 2; ++ks) {
            bf16x8 af = *(const bf16x8*)(&As[wave * 16 + (lane & 15)][ks * 32 + (lane >> 4) * 8]);
#pragma unroll
            for (int nb = 0; nb < 4; ++nb) {
                bf16x8 bfr = *(const bf16x8*)(&Bs[nb * 16 + (lane & 15)][ks * 32 + (lane >> 4) * 8]);
                acc[nb] = __builtin_amdgcn_mfma_f32_16x16x32_bf16(af, bfr, acc[nb], 0, 0, 0);
            }
        }
        __syncthreads();
    }
    const int col = lane & 15, rq = (lane >> 4) * 4;
#pragma unroll
    for (int nb = 0; nb < 4; ++nb)
#pragma unroll
        for (int r = 0; r < 4; ++r) {
            int m = m0 + wave * 16 + rq + r, n = n0 + nb * 16 + col;
            if (n < N) atomicAdd(&Cacc[(size_t)m * N + n], acc[nb][r]);
        }
}

// epilogues: bias + leaky-relu -> bf16 (feeds next MFMA GEMM) / bias only -> fp32
__global__ void ep_lrelu_bf16(const float* __restrict__ acc, const float* __restrict__ bias,
                              __bf16* __restrict__ out, int M, int N) {
    int i = blockIdx.x * blockDim.x + threadIdx.x;
    if (i < M * N) {
        float v = acc[i] + bias[i % N];
        out[i] = (__bf16)(v > 0.f ? v : v * kSlope);
    }
}
__global__ void ep_bias_f32(const float* __restrict__ acc, const float* __restrict__ bias,
                            float* __restrict__ out, int M, int N) {
    int i = blockIdx.x * blockDim.x + threadIdx.x;
    if (i < M * N) out[i] = acc[i] + bias[i % N];
}

// ---------------------------------------------------------------------------
// xih[(s*B+b)*4H + j] = emb[q[b,s]] . w_ih[j,:] + b_ih[j] + b_hh[j]
__global__ __launch_bounds__(256) void xih_gemm(
    const int* __restrict__ questions, const float* __restrict__ emb,
    const float* __restrict__ w_ih, const float* __restrict__ b_ih,
    const float* __restrict__ b_hh, float* __restrict__ xih) {
    __shared__ float As[64][17];
    __shared__ float Bs[64][17];
    __shared__ int qs[64];
    const int m0 = blockIdx.x * 64, j0 = blockIdx.y * 64;
    const int tid = threadIdx.x, tx = tid % 16, ty = tid / 16;
    if (tid < 64) {
        int m = m0 + tid;
        int s = m / kB, b = m % kB;
        qs[tid] = questions[b * kS + s];
    }
    __syncthreads();
    float acc[4][4] = {};
    for (int k0 = 0; k0 < kE; k0 += 16) {
        for (int i = tid; i < 1024; i += 256) {
            int r = i / 16, c = i % 16;
            As[r][c] = emb[(size_t)qs[r] * kE + k0 + c];
        }
        for (int i = tid; i < 1024; i += 256) {
            int r = i / 16, c = i % 16;
            Bs[r][c] = w_ih[(size_t)(j0 + r) * kE + k0 + c];
        }
        __syncthreads();
#pragma unroll
        for (int kk = 0; kk < 16; ++kk) {
            float a[4], bl[4];
#pragma unroll
            for (int i = 0; i < 4; ++i) a[i] = As[ty * 4 + i][kk];
#pragma unroll
            for (int j = 0; j < 4; ++j) bl[j] = Bs[tx * 4 + j][kk];
#pragma unroll
            for (int i = 0; i < 4; ++i)
#pragma unroll
                for (int j = 0; j < 4; ++j) acc[i][j] += a[i] * bl[j];
        }
        __syncthreads();
    }
#pragma unroll
    for (int i = 0; i < 4; ++i)
#pragma unroll
        for (int j = 0; j < 4; ++j) {
            int m = m0 + ty * 4 + i, jj = j0 + tx * 4 + j;
            xih[(size_t)m * 1024 + jj] = acc[i][j] + b_ih[jj] + b_hh[jj];
        }
}

// ---------------------------------------------------------------------------
// One LSTM step: gates = xih_t + h_prev @ w_hh^T, then c/h update.
__global__ __launch_bounds__(256) void lstm_step(
    const float* __restrict__ xih_t, const float* __restrict__ w_hh,
    const float* __restrict__ h_prev, const float* __restrict__ c_prev,
    float* __restrict__ h_new, float* __restrict__ c_new) {
    __shared__ float As[32][33];
    __shared__ float Ws[4][32][33];
    const int b0 = blockIdx.x * 32, j0 = blockIdx.y * 32;
    const int tid = threadIdx.x, tj = tid % 16, tb = tid / 16;
    float acc[4][2][2] = {};
    for (int k0 = 0; k0 < kH; k0 += 32) {
        for (int i = tid; i < 32 * 32; i += 256) {
            int r = i / 32, c = i % 32;
            As[r][c] = h_prev[(size_t)(b0 + r) * kH + k0 + c];
        }
        for (int i = tid; i < 4 * 32 * 32; i += 256) {
            int g = i / 1024, rem = i % 1024, r = rem / 32, c = rem % 32;
            Ws[g][r][c] = w_hh[(size_t)(g * kH + j0 + r) * kH + k0 + c];
        }
        __syncthreads();
#pragma unroll
        for (int kk = 0; kk < 32; ++kk) {
            float a0 = As[tb * 2 + 0][kk], a1 = As[tb * 2 + 1][kk];
#pragma unroll
            for (int g = 0; g < 4; ++g) {
                float w0 = Ws[g][tj * 2 + 0][kk], w1 = Ws[g][tj * 2 + 1][kk];
                acc[g][0][0] += a0 * w0; acc[g][0][1] += a0 * w1;
                acc[g][1][0] += a1 * w0; acc[g][1][1] += a1 * w1;
            }
        }
        __syncthreads();
    }
#pragma unroll
    for (int bb = 0; bb < 2; ++bb)
#pragma unroll
        for (int jj = 0; jj < 2; ++jj) {
            int b = b0 + tb * 2 + bb, j = j0 + tj * 2 + jj;
            float gi = acc[0][bb][jj] + xih_t[(size_t)b * 1024 + 0 * kH + j];
            float gf = acc[1][bb][jj] + xih_t[(size_t)b * 1024 + 1 * kH + j];
            float gg = acc[2][bb][jj] + xih_t[(size_t)b * 1024 + 2 * kH + j];
            float go = acc[3][bb][jj] + xih_t[(size_t)b * 1024 + 3 * kH + j];
            float i_ = 1.f / (1.f + expf(-gi));
            float f_ = 1.f / (1.f + expf(-gf));
            float g_ = tanhf(gg);
            float o_ = 1.f / (1.f + expf(-go));
            float c = f_ * c_prev[(size_t)b * kH + j] + i_ * g_;
            c_new[(size_t)b * kH + j] = c;
            h_new[(size_t)b * kH + j] = o_ * tanhf(c);
        }
}

__global__ void bias_relu(const float* __restrict__ acc, const float* __restrict__ bias,
                          float* __restrict__ out, int M, int N) {
    int i = blockIdx.x * blockDim.x + threadIdx.x;
    if (i < M * N) {
        int n = i % N;
        out[i] = fmaxf(acc[i] + bias[n], 0.f);
    }
}

// ---------------------------------------------------------------------------
// Fused per-sample conv1(3->16) + conv2(16->16), 3x3, pad 1, NO activation between.
// Output written as bf16 (feeds the lin1 MFMA GEMM).
__global__ __launch_bounds__(256) void conv_fused(
    const float* __restrict__ img, const float* __restrict__ all_w,
    __bf16* __restrict__ out) {
    const int b = blockIdx.y;
    const int y0 = blockIdx.x * 8;
    __shared__ float in_s[3][12][66];
    __shared__ float mid_s[16][10][66];
    __shared__ float w1_s[448];
    __shared__ float w2_s[2320];
    const int tid = threadIdx.x;
    const float* wb = all_w + (size_t)b * kTotalW;
    for (int i = tid; i < 448; i += 256) w1_s[i] = wb[i];
    for (int i = tid; i < 2320; i += 256) w2_s[i] = wb[448 + i];
    for (int i = tid; i < 3 * 12 * 66; i += 256) {
        int c = i / (12 * 66), rem = i % (12 * 66), r = rem / 66, x = rem % 66;
        int gy = y0 - 2 + r, gx = x - 1;
        float v = 0.f;
        if (gy >= 0 && gy < 64 && gx >= 0 && gx < 64)
            v = img[(((size_t)b * 3 + c) * 64 + gy) * 64 + gx];
        in_s[c][r][x] = v;
    }
    __syncthreads();
    for (int i = tid; i < 16 * 10 * 64; i += 256) {
        int o = i / 640, rem = i % 640, r = rem / 64, x = rem % 64;
        int gy = y0 - 1 + r;
        float acc = 0.f;
        if (gy >= 0 && gy < 64) {
            acc = w1_s[432 + o];
#pragma unroll
            for (int c = 0; c < 3; ++c)
#pragma unroll
                for (int dy = 0; dy < 3; ++dy)
#pragma unroll
                    for (int dx = 0; dx < 3; ++dx)
                        acc += in_s[c][r + dy][x + dx] * w1_s[(o * 3 + c) * 9 + dy * 3 + dx];
        }
        mid_s[o][r][x + 1] = acc;
    }
    if (tid < 160) {
        int o = tid / 10, r = tid % 10;
        mid_s[o][r][0] = 0.f;
        mid_s[o][r][65] = 0.f;
    }
    __syncthreads();
    const int x = tid & 63, ry = tid >> 6;
#pragma unroll
    for (int rr = 0; rr < 2; ++rr) {
        int r = ry + rr * 4;
        float acc[16];
#pragma unroll
        for (int o = 0; o < 16; ++o) acc[o] = w2_s[2304 + o];
        for (int c = 0; c < 16; ++c) {
#pragma unroll
            for (int dy = 0; dy < 3; ++dy) {
                float v0 = mid_s[c][r + dy][x + 0];
                float v1 = mid_s[c][r + dy][x + 1];
                float v2 = mid_s[c][r + dy][x + 2];
#pragma unroll
                for (int o = 0; o < 16; ++o) {
                    const float* w = &w2_s[(o * 16 + c) * 9 + dy * 3];
                    acc[o] += v0 * w[0] + v1 * w[1] + v2 * w[2];
                }
            }
        }
#pragma unroll
        for (int o = 0; o < 16; ++o)
            out[(((size_t)b * 16 + o) * 64 + (y0 + r)) * 64 + x] = (__bf16)acc[o];
    }
}

// ---------------------------------------------------------------------------
// Fused lin2+lin3: out(256,2). grid B, block 64.
__global__ __launch_bounds__(64) void lin23(
    const float* __restrict__ l1out,
    const float* __restrict__ lw2, const float* __restrict__ lb2,
    const float* __restrict__ lw3, const float* __restrict__ lb3,
    float* __restrict__ out) {
    const int b = blockIdx.x, j = threadIdx.x;
    __shared__ float row[512];
    __shared__ float s[64];
    for (int i = j; i < 512; i += 64) row[i] = l1out[(size_t)b * 512 + i];
    __syncthreads();
    float acc = lb2[j];
    for (int k = 0; k < 512; ++k) acc += row[k] * lw2[(size_t)k * 64 + j];
    s[j] = fmaxf(acc, 0.f);
    __syncthreads();
    if (j < 2) {
        float o = lb3[j];
        for (int k = 0; k < 64; ++k) o += s[k] * lw3[(size_t)k * 2 + j];
        out[(size_t)b * 2 + j] = o;
    }
}

// ---------------------------------------------------------------------------
extern "C" void kernel_launch(void* const* d_in, const int* in_sizes, int n_in,
                              void* d_out, int out_size, void* d_ws, size_t ws_size,
                              hipStream_t stream) {
    const int* questions = (const int*)d_in[0];
    const float* images  = (const float*)d_in[1];
    const float* emb     = (const float*)d_in[2];
    const float* w_ih    = (const float*)d_in[3];
    const float* w_hh    = (const float*)d_in[4];
    const float* b_ih    = (const float*)d_in[5];
    const float* b_hh    = (const float*)d_in[6];
    const float* hw1     = (const float*)d_in[7];
    const float* hb1     = (const float*)d_in[8];
    const float* hw2     = (const float*)d_in[9];
    const float* hb2     = (const float*)d_in[10];
    const float* hw3     = (const float*)d_in[11];
    const float* hb3     = (const float*)d_in[12];
    const float* lw1     = (const float*)d_in[13];
    const float* lb1     = (const float*)d_in[14];
    const float* lw2     = (const float*)d_in[15];
    const float* lb2     = (const float*)d_in[16];
    const float* lw3     = (const float*)d_in[17];
    const float* lb3     = (const float*)d_in[18];
    float* out = (float*)d_out;

    char* ws = (char*)d_ws;
    size_t off = 0;
    auto alloc = [&](size_t nbytes) -> void* {
        void* p = (void*)(ws + off);
        off += (nbytes + 255) & ~(size_t)255;
        return p;
    };
    // big (64MB) timeline (single stream, strictly ordered):
    //   [0..20MB)  xih fp32            (dead after LSTM)
    //   [24..47MB) w3t bf16            (dead after hw3 MFMA GEMM)
    //   [0..32MB)  conv out bf16       (written by conv_fused, after both above are dead)
    float*  big  = (float*)alloc(64ull << 20);
    __bf16* lw1t = (__bf16*)alloc((size_t)512 * 65536 * 2);    // lw1^T bf16 (N=512 x K=65536)
    float*  hc0  = (float*)alloc(2 * kB * kH * sizeof(float));
    float*  hc1  = (float*)alloc(2 * kB * kH * sizeof(float));
    __bf16* w1t  = (__bf16*)alloc((size_t)1024 * 256 * 2);     // hw1^T bf16
    __bf16* w2t  = (__bf16*)alloc((size_t)4096 * 1024 * 2);    // hw2^T bf16
    __bf16* h0b  = (__bf16*)alloc((size_t)kB * kH * 2);
    __bf16* h1b  = (__bf16*)alloc((size_t)kB * 1024 * 2);
    __bf16* h2b  = (__bf16*)alloc((size_t)kB * 4096 * 2);
    // contiguous fp32 accumulators (zeroed in one kernel): hw1 | hw2 | hw3 | lin1
    float*  accz = (float*)alloc((size_t)kB * (1024 + 4096 + 2768 + 512) * sizeof(float));
    float*  accA = accz;
    float*  accB = accA + (size_t)kB * 1024;
    float*  accC = accB + (size_t)kB * 4096;
    float*  acc1 = accC + (size_t)kB * 2768;
    float*  allw = (float*)alloc((size_t)kB * kTotalW * sizeof(float));
    float*  l1out= (float*)alloc((size_t)kB * 512 * sizeof(float));

    float*  xih    = big;
    __bf16* c2out  = (__bf16*)big;
    __bf16* w3t    = (__bf16*)((char*)big + (24ull << 20));    // 2768 x 4096 bf16 = 22.7MB
    float* hbuf[2] = {hc0, hc1};
    float* cbuf[2] = {hc0 + kB * kH, hc1 + kB * kH};

    const int nACC = kB * (1024 + 4096 + 2768 + 512);
    zero_f32<<<512, 256, 0, stream>>>(accz, nACC);
    zero_f32<<<256, 256, 0, stream>>>(hc0, 2 * kB * kH);       // h0=c0=0

    // weight transposes+converts (regions disjoint from their concurrent readers/writers)
    transpose_cvt<<<dim3(8, 32),   256, 0, stream>>>(hw1, w1t, 256, 1024);
    transpose_cvt<<<dim3(32, 128), 256, 0, stream>>>(hw2, w2t, 1024, 4096);
    transpose_cvt<<<dim3(128, 87), 256, 0, stream>>>(hw3, w3t, 4096, 2768);
    transpose_cvt<<<dim3(2048, 16), 256, 0, stream>>>(lw1, lw1t, 65536, 512);

    // 1) xih = emb[q] @ w_ih^T + b_ih + b_hh, laid out (S,B,4H)
    xih_gemm<<<dim3(80, 16), 256, 0, stream>>>(questions, emb, w_ih, b_ih, b_hh, xih);

    // 2) 20 LSTM steps (ping-pong h/c)
    for (int t = 0; t < kS; ++t) {
        lstm_step<<<dim3(8, 8), 256, 0, stream>>>(
            xih + (size_t)t * kB * 1024, w_hh,
            hbuf[t & 1], cbuf[t & 1], hbuf[(t + 1) & 1], cbuf[(t + 1) & 1]);
    }
    const float* hfin = hbuf[0];  // t=19 writes buffer 0
    cvt_bf16<<<64, 256, 0, stream>>>(hfin, h0b, kB * kH);

    // 3) hyper-MLP via bf16 MFMA split-K GEMMs
    mfma_splitk<<<dim3(4, 16, 4), 256, 0, stream>>>(h0b, w1t, accA, 256, 1024, 256, 64);
    ep_lrelu_bf16<<<1024, 256, 0, stream>>>(accA, hb1, h1b, 256, 1024);
    mfma_splitk<<<dim3(4, 64, 4), 256, 0, stream>>>(h1b, w2t, accB, 256, 4096, 1024, 256);
    ep_lrelu_bf16<<<4096, 256, 0, stream>>>(accB, hb2, h2b, 256, 4096);
    mfma_splitk<<<dim3(4, 44, 8), 256, 0, stream>>>(h2b, w3t, accC, 256, 2768, 4096, 512);
    ep_bias_f32<<<2768, 256, 0, stream>>>(accC, hb3, allw, 256, 2768);

    // 4) fused conv1+conv2 with per-sample generated weights -> bf16
    conv_fused<<<dim3(8, 256), 256, 0, stream>>>(images, allw, c2out);

    // 5) lin1 via bf16 MFMA split-K: 256x512, K=65536, splits=32
    mfma_splitk<<<dim3(4, 8, 32), 256, 0, stream>>>(c2out, lw1t, acc1, 256, 512, 65536, 2048);
    bias_relu<<<512, 256, 0, stream>>>(acc1, lb1, l1out, 256, 512);

    // 6) lin2+lin3 fused -> out (256,2)
    lin23<<<256, 64, 0, stream>>>(l1out, lw2, lb2, lw3, lb3, out);
}

// Round 4
// 1226.509 us; speedup vs baseline: 2.2230x; 1.1546x over previous
//
#include <hip/hip_runtime.h>
#include <hip/hip_bf16.h>
#include <math.h>

// Problem constants
constexpr int kB = 256, kS = 20, kE = 128, kH = 256;
constexpr int kTotalW = 2768;           // 432+16 + 2304+16
constexpr float kSlope = 1.0f / 5.5f;

typedef __bf16 bf16x8 __attribute__((ext_vector_type(8)));
typedef float  floatx4 __attribute__((ext_vector_type(4)));

// ---------------------------------------------------------------------------
// zero-fill (ws is poisoned 0xAA every call)
__global__ void zero_f32(float* __restrict__ p, int n) {
    for (int i = blockIdx.x * blockDim.x + threadIdx.x; i < n; i += gridDim.x * blockDim.x)
        p[i] = 0.f;
}

// rowmajor fp32 -> bf16 (RNE)
__global__ void cvt_bf16(const float* __restrict__ in, __bf16* __restrict__ out, int n) {
    for (int i = blockIdx.x * blockDim.x + threadIdx.x; i < n; i += gridDim.x * blockDim.x)
        out[i] = (__bf16)in[i];
}

// W (K x N fp32, row-major) -> Wt (N x K bf16, row-major). grid (K/32, ceil(N/32)), block 256.
__global__ __launch_bounds__(256) void transpose_cvt(
    const float* __restrict__ W, __bf16* __restrict__ Wt, int K, int N) {
    __shared__ float t[32][33];
    const int k0 = blockIdx.x * 32, n0 = blockIdx.y * 32;
    const int tx = threadIdx.x & 31, ty = threadIdx.x >> 5;   // 32 x 8
#pragma unroll
    for (int j = 0; j < 32; j += 8) {
        int n = n0 + tx, k = k0 + ty + j;
        t[ty + j][tx] = (n < N) ? W[(size_t)k * N + n] : 0.f;
    }
    __syncthreads();
#pragma unroll
    for (int j = 0; j < 32; j += 8) {
        int n = n0 + ty + j, k = k0 + tx;
        if (n < N) Wt[(size_t)n * K + k] = (__bf16)t[tx][ty + j];
    }
}

// ---------------------------------------------------------------------------
// bf16 MFMA split-K GEMM: Cacc(M,N fp32, pre-zeroed) += A(MxK bf16) @ Bt(NxK bf16)^T
// 64x64 tile, BK=64, 4 waves x (16 rows x 64 cols), grid (M/64, ceil(N/64), splits).
// Fragment layouts (verified, learn_hip m89/m91): A/B [outer=lane&15][k=(lane>>4)*8+j],
// C/D col=lane&15, row=(lane>>4)*4+reg. LDS rows padded to 72 bf16 -> frag reads 2-way (free).
__global__ __launch_bounds__(256) void mfma_splitk(
    const __bf16* __restrict__ A, const __bf16* __restrict__ Bt,
    float* __restrict__ Cacc, int M, int N, int K, int Kchunk) {
    __shared__ __bf16 As[64][72];
    __shared__ __bf16 Bs[64][72];
    const int m0 = blockIdx.x * 64, n0 = blockIdx.y * 64;
    const int kbeg = blockIdx.z * Kchunk, kend = kbeg + Kchunk;
    const int tid = threadIdx.x, lane = tid & 63, wave = tid >> 6;
    floatx4 acc[4] = {};
    for (int k0 = kbeg; k0 < kend; k0 += 64) {
        for (int i = tid; i < 512; i += 256) {          // A tile: 64 rows x 64 k
            int r = i >> 3, seg = i & 7;
            uint4 v = *(const uint4*)(A + (size_t)(m0 + r) * K + k0 + seg * 8);
            *(uint4*)(&As[r][seg * 8]) = v;
        }
        for (int i = tid; i < 512; i += 256) {          // B^T tile: 64 n-rows x 64 k
            int r = i >> 3, seg = i & 7;
            uint4 v = make_uint4(0u, 0u, 0u, 0u);
            if (n0 + r < N) v = *(const uint4*)(Bt + (size_t)(n0 + r) * K + k0 + seg * 8);
            *(uint4*)(&Bs[r][seg * 8]) = v;
        }
        __syncthreads();
#pragma unroll
        for (int ks = 0; ks < 2; ++ks) {
            bf16x8 af = *(const bf16x8*)(&As[wave * 16 + (lane & 15)][ks * 32 + (lane >> 4) * 8]);
#pragma unroll
            for (int nb = 0; nb < 4; ++nb) {
                bf16x8 bfr = *(const bf16x8*)(&Bs[nb * 16 + (lane & 15)][ks * 32 + (lane >> 4) * 8]);
                acc[nb] = __builtin_amdgcn_mfma_f32_16x16x32_bf16(af, bfr, acc[nb], 0, 0, 0);
            }
        }
        __syncthreads();
    }
    const int col = lane & 15, rq = (lane >> 4) * 4;
#pragma unroll
    for (int nb = 0; nb < 4; ++nb)
#pragma unroll
        for (int r = 0; r < 4; ++r) {
            int m = m0 + wave * 16 + rq + r, n = n0 + nb * 16 + col;
            if (n < N) atomicAdd(&Cacc[(size_t)m * N + n], acc[nb][r]);
        }
}

// epilogues: bias + leaky-relu -> bf16 (feeds next MFMA GEMM) / bias only -> fp32
__global__ void ep_lrelu_bf16(const float* __restrict__ acc, const float* __restrict__ bias,
                              __bf16* __restrict__ out, int M, int N) {
    int i = blockIdx.x * blockDim.x + threadIdx.x;
    if (i < M * N) {
        float v = acc[i] + bias[i % N];
        out[i] = (__bf16)(v > 0.f ? v : v * kSlope);
    }
}
__global__ void ep_bias_f32(const float* __restrict__ acc, const float* __restrict__ bias,
                            float* __restrict__ out, int M, int N) {
    int i = blockIdx.x * blockDim.x + threadIdx.x;
    if (i < M * N) out[i] = acc[i] + bias[i % N];
}

// ---------------------------------------------------------------------------
// xih[(s*B+b)*4H + j] = emb[q[b,s]] . w_ih[j,:] + b_ih[j] + b_hh[j]
__global__ __launch_bounds__(256) void xih_gemm(
    const int* __restrict__ questions, const float* __restrict__ emb,
    const float* __restrict__ w_ih, const float* __restrict__ b_ih,
    const float* __restrict__ b_hh, float* __restrict__ xih) {
    __shared__ float As[64][17];
    __shared__ float Bs[64][17];
    __shared__ int qs[64];
    const int m0 = blockIdx.x * 64, j0 = blockIdx.y * 64;
    const int tid = threadIdx.x, tx = tid % 16, ty = tid / 16;
    if (tid < 64) {
        int m = m0 + tid;
        int s = m / kB, b = m % kB;
        qs[tid] = questions[b * kS + s];
    }
    __syncthreads();
    float acc[4][4] = {};
    for (int k0 = 0; k0 < kE; k0 += 16) {
        for (int i = tid; i < 1024; i += 256) {
            int r = i / 16, c = i % 16;
            As[r][c] = emb[(size_t)qs[r] * kE + k0 + c];
        }
        for (int i = tid; i < 1024; i += 256) {
            int r = i / 16, c = i % 16;
            Bs[r][c] = w_ih[(size_t)(j0 + r) * kE + k0 + c];
        }
        __syncthreads();
#pragma unroll
        for (int kk = 0; kk < 16; ++kk) {
            float a[4], bl[4];
#pragma unroll
            for (int i = 0; i < 4; ++i) a[i] = As[ty * 4 + i][kk];
#pragma unroll
            for (int j = 0; j < 4; ++j) bl[j] = Bs[tx * 4 + j][kk];
#pragma unroll
            for (int i = 0; i < 4; ++i)
#pragma unroll
                for (int j = 0; j < 4; ++j) acc[i][j] += a[i] * bl[j];
        }
        __syncthreads();
    }
#pragma unroll
    for (int i = 0; i < 4; ++i)
#pragma unroll
        for (int j = 0; j < 4; ++j) {
            int m = m0 + ty * 4 + i, jj = j0 + tx * 4 + j;
            xih[(size_t)m * 1024 + jj] = acc[i][j] + b_ih[jj] + b_hh[jj];
        }
}

// ---------------------------------------------------------------------------
// One LSTM step: gates = xih_t + h_prev @ w_hh^T, then c/h update.
__global__ __launch_bounds__(256) void lstm_step(
    const float* __restrict__ xih_t, const float* __restrict__ w_hh,
    const float* __restrict__ h_prev, const float* __restrict__ c_prev,
    float* __restrict__ h_new, float* __restrict__ c_new) {
    __shared__ float As[32][33];
    __shared__ float Ws[4][32][33];
    const int b0 = blockIdx.x * 32, j0 = blockIdx.y * 32;
    const int tid = threadIdx.x, tj = tid % 16, tb = tid / 16;
    float acc[4][2][2] = {};
    for (int k0 = 0; k0 < kH; k0 += 32) {
        for (int i = tid; i < 32 * 32; i += 256) {
            int r = i / 32, c = i % 32;
            As[r][c] = h_prev[(size_t)(b0 + r) * kH + k0 + c];
        }
        for (int i = tid; i < 4 * 32 * 32; i += 256) {
            int g = i / 1024, rem = i % 1024, r = rem / 32, c = rem % 32;
            Ws[g][r][c] = w_hh[(size_t)(g * kH + j0 + r) * kH + k0 + c];
        }
        __syncthreads();
#pragma unroll
        for (int kk = 0; kk < 32; ++kk) {
            float a0 = As[tb * 2 + 0][kk], a1 = As[tb * 2 + 1][kk];
#pragma unroll
            for (int g = 0; g < 4; ++g) {
                float w0 = Ws[g][tj * 2 + 0][kk], w1 = Ws[g][tj * 2 + 1][kk];
                acc[g][0][0] += a0 * w0; acc[g][0][1] += a0 * w1;
                acc[g][1][0] += a1 * w0; acc[g][1][1] += a1 * w1;
            }
        }
        __syncthreads();
    }
#pragma unroll
    for (int bb = 0; bb < 2; ++bb)
#pragma unroll
        for (int jj = 0; jj < 2; ++jj) {
            int b = b0 + tb * 2 + bb, j = j0 + tj * 2 + jj;
            float gi = acc[0][bb][jj] + xih_t[(size_t)b * 1024 + 0 * kH + j];
            float gf = acc[1][bb][jj] + xih_t[(size_t)b * 1024 + 1 * kH + j];
            float gg = acc[2][bb][jj] + xih_t[(size_t)b * 1024 + 2 * kH + j];
            float go = acc[3][bb][jj] + xih_t[(size_t)b * 1024 + 3 * kH + j];
            float i_ = 1.f / (1.f + expf(-gi));
            float f_ = 1.f / (1.f + expf(-gf));
            float g_ = tanhf(gg);
            float o_ = 1.f / (1.f + expf(-go));
            float c = f_ * c_prev[(size_t)b * kH + j] + i_ * g_;
            c_new[(size_t)b * kH + j] = c;
            h_new[(size_t)b * kH + j] = o_ * tanhf(c);
        }
}

__global__ void bias_relu(const float* __restrict__ acc, const float* __restrict__ bias,
                          float* __restrict__ out, int M, int N) {
    int i = blockIdx.x * blockDim.x + threadIdx.x;
    if (i < M * N) {
        int n = i % N;
        out[i] = fmaxf(acc[i] + bias[n], 0.f);
    }
}

// ---------------------------------------------------------------------------
// MFMA implicit-GEMM fused conv1(3->16,K27) + conv2(16->16,K144), 3x3, pad 1,
// no activation between. One block = one sample x one 8-row output slab.
// conv1: im2col tile col1[640 px][k<=32 pad] bf16, A=w1[16 o][32 k], 40 MFMAs.
// conv2: tap-pair decomposition, K=144 -> 5 MFMA K=32 (pair p: k<16 tap 2p,
// k>=16 tap 2p+1; tap 9 = A zeros). mid stored channel-contiguous [10][66][24]
// bf16 (48B col stride: 16B-aligned b128, <=2-way banks).
// Zero-padding semantics of conv2 over conv1's output reproduced exactly by
// writing 0 (not bias) to mid rows with gy outside [0,64) and zero border cols.
constexpr int C1K = 40;    // col1 row stride in bf16 (80B: 16B-aligned, 2-way banks)
constexpr int MIDC = 24;   // mid channel stride in bf16 (48B cols)

__global__ __launch_bounds__(256) void conv_fused_mfma(
    const float* __restrict__ img,     // (B,3,64,64)
    const float* __restrict__ all_w,   // (B,2768)
    __bf16* __restrict__ out) {        // (B,16,64,64) bf16
    const int b = blockIdx.y;
    const int y0 = blockIdx.x * 8;
    __shared__ __bf16 w1a[16 * 32];        // [o][k], k=c*9+dy*3+dx, pad k>=27
    __shared__ __bf16 w2a[5 * 16 * 32];    // [pair][o][k]
    __shared__ float  bias_s[32];          // [0:16) conv1 bias, [16:32) conv2 bias
    __shared__ __bf16 un[640 * C1K];       // union: col1[640][C1K] 51.2KB / mid[10][66][MIDC] 31.7KB
    __bf16* col1 = un;
    __bf16* mid  = un;

    const int tid = threadIdx.x, lane = tid & 63, wave = tid >> 6;
    const float* wb = all_w + (size_t)b * kTotalW;

    // ---- phase A: weight fragments + biases + im2col ----
    for (int i = tid; i < 512; i += 256) {               // w1a
        int o = i >> 5, k = i & 31;
        w1a[i] = (__bf16)((k < 27) ? wb[o * 27 + k] : 0.f);
    }
    for (int i = tid; i < 5 * 16 * 32; i += 256) {       // w2a
        int p = i >> 9, rem = i & 511, o = rem >> 5, k = rem & 31;
        int t = 2 * p + (k >> 4), c = k & 15;
        w2a[i] = (__bf16)((t < 9) ? wb[448 + (o * 16 + c) * 9 + t] : 0.f);
    }
    if (tid < 16) bias_s[tid] = wb[432 + tid];
    else if (tid < 32) bias_s[tid] = wb[448 + 2304 + (tid - 16)];
    // im2col, k-outer / pixel-inner (coalesced img reads). px p=(r,x): mid row
    // gy_mid=y0-1+r, r in [0,10), x in [0,64). k<27: c=k/9, tap=(dy,dx).
    for (int i = tid; i < 32 * 640; i += 256) {
        int k = i / 640, p = i - k * 640;
        int r = p >> 6, x = p & 63;
        float v = 0.f;
        if (k < 27) {
            int c = k / 9, t = k - c * 9, dy = t / 3, dx = t - dy * 3;
            int gy = y0 - 2 + r + dy, gx = x + dx - 1;
            if (gy >= 0 && gy < 64 && gx >= 0 && gx < 64)
                v = img[(((size_t)b * 3 + c) << 12) + (gy << 6) + gx];
        }
        col1[p * C1K + k] = (__bf16)v;
    }
    __syncthreads();

    // ---- phase B: conv1 MFMAs (reads col1) ----
    bf16x8 a1 = *(const bf16x8*)&w1a[(lane & 15) * 32 + (lane >> 4) * 8];
    floatx4 d1[10];
#pragma unroll
    for (int ti = 0; ti < 10; ++ti) {
        int tile = wave * 10 + ti;
        bf16x8 bf = *(const bf16x8*)&col1[(tile * 16 + (lane & 15)) * C1K + (lane >> 4) * 8];
        floatx4 z = {};
        d1[ti] = __builtin_amdgcn_mfma_f32_16x16x32_bf16(a1, bf, z, 0, 0, 0);
    }
    __syncthreads();   // all col1 reads done; union becomes mid

    // ---- phase C: write mid (bias; exact 0 for out-of-range rows), zero border cols ----
    {
        const int o0 = (lane >> 4) * 4;
#pragma unroll
        for (int ti = 0; ti < 10; ++ti) {
            int tile = wave * 10 + ti;
            int p = tile * 16 + (lane & 15);
            int r = p >> 6, x = p & 63;
            int gy = y0 - 1 + r;
            union { short4 s4; __bf16 h[4]; } u;
#pragma unroll
            for (int q = 0; q < 4; ++q) {
                float v = (gy >= 0 && gy < 64) ? (d1[ti][q] + bias_s[o0 + q]) : 0.f;
                u.h[q] = (__bf16)v;
            }
            *(short4*)&mid[(r * 66 + (x + 1)) * MIDC + o0] = u.s4;
        }
    }
    for (int i = tid; i < 480; i += 256) {   // cols 0 and 65 = conv2 x-padding
        int r = i / 48, rem = i % 48, cc = rem / 24, ch = rem % 24;
        mid[(r * 66 + (cc ? 65 : 0)) * MIDC + ch] = (__bf16)0.f;
    }
    __syncthreads();

    // ---- phase D: conv2, 32 tiles (8 rows x 4 x-tiles), 8 per wave ----
    bf16x8 a2[5];
#pragma unroll
    for (int p = 0; p < 5; ++p)
        a2[p] = *(const bf16x8*)&w2a[p * 512 + (lane & 15) * 32 + (lane >> 4) * 8];
    const int half = lane >> 5;              // which tap of the pair this lane feeds
    const int c0 = ((lane >> 4) & 1) * 8;    // channel offset within the tap
    const int n = lane & 15;
    const int o0 = (lane >> 4) * 4;
#pragma unroll
    for (int ti = 0; ti < 8; ++ti) {
        int tile = wave * 8 + ti;
        int rr = tile >> 2, xt = (tile & 3) * 16;
        floatx4 acc = {};
#pragma unroll
        for (int p = 0; p < 5; ++p) {
            int t = 2 * p + half;
            int dy = 0, dx = 0;
            if (t < 9) { dy = t / 3; dx = t - dy * 3; }   // t==9: A is zero, any valid B addr
            bf16x8 bf = *(const bf16x8*)&mid[((rr + dy) * 66 + (xt + n + dx)) * MIDC + c0];
            acc = __builtin_amdgcn_mfma_f32_16x16x32_bf16(a2[p], bf, acc, 0, 0, 0);
        }
        int gy = y0 + rr, gx = xt + n;
#pragma unroll
        for (int q = 0; q < 4; ++q)
            out[(((size_t)b * 16 + o0 + q) * 64 + gy) * 64 + gx] =
                (__bf16)(acc[q] + bias_s[16 + o0 + q]);
    }
}

// ---------------------------------------------------------------------------
// Fused lin2+lin3: out(256,2). grid B, block 64.
__global__ __launch_bounds__(64) void lin23(
    const float* __restrict__ l1out,
    const float* __restrict__ lw2, const float* __restrict__ lb2,
    const float* __restrict__ lw3, const float* __restrict__ lb3,
    float* __restrict__ out) {
    const int b = blockIdx.x, j = threadIdx.x;
    __shared__ float row[512];
    __shared__ float s[64];
    for (int i = j; i < 512; i += 64) row[i] = l1out[(size_t)b * 512 + i];
    __syncthreads();
    float acc = lb2[j];
    for (int k = 0; k < 512; ++k) acc += row[k] * lw2[(size_t)k * 64 + j];
    s[j] = fmaxf(acc, 0.f);
    __syncthreads();
    if (j < 2) {
        float o = lb3[j];
        for (int k = 0; k < 64; ++k) o += s[k] * lw3[(size_t)k * 2 + j];
        out[(size_t)b * 2 + j] = o;
    }
}

// ---------------------------------------------------------------------------
extern "C" void kernel_launch(void* const* d_in, const int* in_sizes, int n_in,
                              void* d_out, int out_size, void* d_ws, size_t ws_size,
                              hipStream_t stream) {
    const int* questions = (const int*)d_in[0];
    const float* images  = (const float*)d_in[1];
    const float* emb     = (const float*)d_in[2];
    const float* w_ih    = (const float*)d_in[3];
    const float* w_hh    = (const float*)d_in[4];
    const float* b_ih    = (const float*)d_in[5];
    const float* b_hh    = (const float*)d_in[6];
    const float* hw1     = (const float*)d_in[7];
    const float* hb1     = (const float*)d_in[8];
    const float* hw2     = (const float*)d_in[9];
    const float* hb2     = (const float*)d_in[10];
    const float* hw3     = (const float*)d_in[11];
    const float* hb3     = (const float*)d_in[12];
    const float* lw1     = (const float*)d_in[13];
    const float* lb1     = (const float*)d_in[14];
    const float* lw2     = (const float*)d_in[15];
    const float* lb2     = (const float*)d_in[16];
    const float* lw3     = (const float*)d_in[17];
    const float* lb3     = (const float*)d_in[18];
    float* out = (float*)d_out;

    char* ws = (char*)d_ws;
    size_t off = 0;
    auto alloc = [&](size_t nbytes) -> void* {
        void* p = (void*)(ws + off);
        off += (nbytes + 255) & ~(size_t)255;
        return p;
    };
    // big (64MB) timeline (single stream, strictly ordered):
    //   [0..20MB)  xih fp32            (dead after LSTM)
    //   [24..47MB) w3t bf16            (dead after hw3 MFMA GEMM)
    //   [0..32MB)  conv out bf16       (written by conv_fused_mfma, after both above dead)
    float*  big  = (float*)alloc(64ull << 20);
    __bf16* lw1t = (__bf16*)alloc((size_t)512 * 65536 * 2);    // lw1^T bf16 (N=512 x K=65536)
    float*  hc0  = (float*)alloc(2 * kB * kH * sizeof(float));
    float*  hc1  = (float*)alloc(2 * kB * kH * sizeof(float));
    __bf16* w1t  = (__bf16*)alloc((size_t)1024 * 256 * 2);     // hw1^T bf16
    __bf16* w2t  = (__bf16*)alloc((size_t)4096 * 1024 * 2);    // hw2^T bf16
    __bf16* h0b  = (__bf16*)alloc((size_t)kB * kH * 2);
    __bf16* h1b  = (__bf16*)alloc((size_t)kB * 1024 * 2);
    __bf16* h2b  = (__bf16*)alloc((size_t)kB * 4096 * 2);
    // contiguous fp32 accumulators (zeroed in one kernel): hw1 | hw2 | hw3 | lin1
    float*  accz = (float*)alloc((size_t)kB * (1024 + 4096 + 2768 + 512) * sizeof(float));
    float*  accA = accz;
    float*  accB = accA + (size_t)kB * 1024;
    float*  accC = accB + (size_t)kB * 4096;
    float*  acc1 = accC + (size_t)kB * 2768;
    float*  allw = (float*)alloc((size_t)kB * kTotalW * sizeof(float));
    float*  l1out= (float*)alloc((size_t)kB * 512 * sizeof(float));

    float*  xih    = big;
    __bf16* c2out  = (__bf16*)big;
    __bf16* w3t    = (__bf16*)((char*)big + (24ull << 20));    // 2768 x 4096 bf16 = 22.7MB
    float* hbuf[2] = {hc0, hc1};
    float* cbuf[2] = {hc0 + kB * kH, hc1 + kB * kH};

    const int nACC = kB * (1024 + 4096 + 2768 + 512);
    zero_f32<<<512, 256, 0, stream>>>(accz, nACC);
    zero_f32<<<256, 256, 0, stream>>>(hc0, 2 * kB * kH);       // h0=c0=0

    // weight transposes+converts (regions disjoint from their concurrent readers/writers)
    transpose_cvt<<<dim3(8, 32),   256, 0, stream>>>(hw1, w1t, 256, 1024);
    transpose_cvt<<<dim3(32, 128), 256, 0, stream>>>(hw2, w2t, 1024, 4096);
    transpose_cvt<<<dim3(128, 87), 256, 0, stream>>>(hw3, w3t, 4096, 2768);
    transpose_cvt<<<dim3(2048, 16), 256, 0, stream>>>(lw1, lw1t, 65536, 512);

    // 1) xih = emb[q] @ w_ih^T + b_ih + b_hh, laid out (S,B,4H)
    xih_gemm<<<dim3(80, 16), 256, 0, stream>>>(questions, emb, w_ih, b_ih, b_hh, xih);

    // 2) 20 LSTM steps (ping-pong h/c)
    for (int t = 0; t < kS; ++t) {
        lstm_step<<<dim3(8, 8), 256, 0, stream>>>(
            xih + (size_t)t * kB * 1024, w_hh,
            hbuf[t & 1], cbuf[t & 1], hbuf[(t + 1) & 1], cbuf[(t + 1) & 1]);
    }
    const float* hfin = hbuf[0];  // t=19 writes buffer 0
    cvt_bf16<<<64, 256, 0, stream>>>(hfin, h0b, kB * kH);

    // 3) hyper-MLP via bf16 MFMA split-K GEMMs
    mfma_splitk<<<dim3(4, 16, 4), 256, 0, stream>>>(h0b, w1t, accA, 256, 1024, 256, 64);
    ep_lrelu_bf16<<<1024, 256, 0, stream>>>(accA, hb1, h1b, 256, 1024);
    mfma_splitk<<<dim3(4, 64, 4), 256, 0, stream>>>(h1b, w2t, accB, 256, 4096, 1024, 256);
    ep_lrelu_bf16<<<4096, 256, 0, stream>>>(accB, hb2, h2b, 256, 4096);
    mfma_splitk<<<dim3(4, 44, 8), 256, 0, stream>>>(h2b, w3t, accC, 256, 2768, 4096, 512);
    ep_bias_f32<<<2768, 256, 0, stream>>>(accC, hb3, allw, 256, 2768);

    // 4) fused conv1+conv2 via MFMA implicit GEMM -> bf16
    conv_fused_mfma<<<dim3(8, 256), 256, 0, stream>>>(images, allw, c2out);

    // 5) lin1 via bf16 MFMA split-K: 256x512, K=65536, splits=32
    mfma_splitk<<<dim3(4, 8, 32), 256, 0, stream>>>(c2out, lw1t, acc1, 256, 512, 65536, 2048);
    bias_relu<<<512, 256, 0, stream>>>(acc1, lb1, l1out, 256, 512);

    // 6) lin2+lin3 fused -> out (256,2)
    lin23<<<256, 64, 0, stream>>>(l1out, lw2, lb2, lw3, lb3, out);
}

// Round 5
// 1145.604 us; speedup vs baseline: 2.3800x; 1.0706x over previous
//
#include <hip/hip_runtime.h>
#include <hip/hip_bf16.h>
#include <math.h>

// Problem constants
constexpr int kB = 256, kS = 20, kE = 128, kH = 256;
constexpr int kTotalW = 2768;           // 432+16 + 2304+16
constexpr float kSlope = 1.0f / 5.5f;

typedef __bf16 bf16x8 __attribute__((ext_vector_type(8)));
typedef float  floatx4 __attribute__((ext_vector_type(4)));

// ---------------------------------------------------------------------------
// zero-fill (ws is poisoned 0xAA every call)
__global__ void zero_f32(float* __restrict__ p, int n) {
    for (int i = blockIdx.x * blockDim.x + threadIdx.x; i < n; i += gridDim.x * blockDim.x)
        p[i] = 0.f;
}

// rowmajor fp32 -> bf16 (RNE)
__global__ void cvt_bf16(const float* __restrict__ in, __bf16* __restrict__ out, int n) {
    for (int i = blockIdx.x * blockDim.x + threadIdx.x; i < n; i += gridDim.x * blockDim.x)
        out[i] = (__bf16)in[i];
}

// W (K x N fp32, row-major) -> Wt (N x K bf16, row-major). grid (K/32, ceil(N/32)), block 256.
__global__ __launch_bounds__(256) void transpose_cvt(
    const float* __restrict__ W, __bf16* __restrict__ Wt, int K, int N) {
    __shared__ float t[32][33];
    const int k0 = blockIdx.x * 32, n0 = blockIdx.y * 32;
    const int tx = threadIdx.x & 31, ty = threadIdx.x >> 5;   // 32 x 8
#pragma unroll
    for (int j = 0; j < 32; j += 8) {
        int n = n0 + tx, k = k0 + ty + j;
        t[ty + j][tx] = (n < N) ? W[(size_t)k * N + n] : 0.f;
    }
    __syncthreads();
#pragma unroll
    for (int j = 0; j < 32; j += 8) {
        int n = n0 + ty + j, k = k0 + tx;
        if (n < N) Wt[(size_t)n * K + k] = (__bf16)t[tx][ty + j];
    }
}

// ---------------------------------------------------------------------------
// bf16 MFMA split-K GEMM: Cacc(M,N fp32, pre-zeroed) += A(MxK bf16) @ Bt(NxK bf16)^T
// 64x64 tile, BK=64, 4 waves x (16 rows x 64 cols), grid (M/64, ceil(N/64), splits).
// Fragment layouts (verified): A/B [outer=lane&15][k=(lane>>4)*8+j],
// C/D col=lane&15, row=(lane>>4)*4+reg. LDS rows padded to 72 bf16 -> 2-way banks (free).
__global__ __launch_bounds__(256) void mfma_splitk(
    const __bf16* __restrict__ A, const __bf16* __restrict__ Bt,
    float* __restrict__ Cacc, int M, int N, int K, int Kchunk) {
    __shared__ __bf16 As[64][72];
    __shared__ __bf16 Bs[64][72];
    const int m0 = blockIdx.x * 64, n0 = blockIdx.y * 64;
    const int kbeg = blockIdx.z * Kchunk, kend = kbeg + Kchunk;
    const int tid = threadIdx.x, lane = tid & 63, wave = tid >> 6;
    floatx4 acc[4] = {};
    for (int k0 = kbeg; k0 < kend; k0 += 64) {
        for (int i = tid; i < 512; i += 256) {          // A tile: 64 rows x 64 k
            int r = i >> 3, seg = i & 7;
            uint4 v = *(const uint4*)(A + (size_t)(m0 + r) * K + k0 + seg * 8);
            *(uint4*)(&As[r][seg * 8]) = v;
        }
        for (int i = tid; i < 512; i += 256) {          // B^T tile: 64 n-rows x 64 k
            int r = i >> 3, seg = i & 7;
            uint4 v = make_uint4(0u, 0u, 0u, 0u);
            if (n0 + r < N) v = *(const uint4*)(Bt + (size_t)(n0 + r) * K + k0 + seg * 8);
            *(uint4*)(&Bs[r][seg * 8]) = v;
        }
        __syncthreads();
#pragma unroll
        for (int ks = 0; ks < 2; ++ks) {
            bf16x8 af = *(const bf16x8*)(&As[wave * 16 + (lane & 15)][ks * 32 + (lane >> 4) * 8]);
#pragma unroll
            for (int nb = 0; nb < 4; ++nb) {
                bf16x8 bfr = *(const bf16x8*)(&Bs[nb * 16 + (lane & 15)][ks * 32 + (lane >> 4) * 8]);
                acc[nb] = __builtin_amdgcn_mfma_f32_16x16x32_bf16(af, bfr, acc[nb], 0, 0, 0);
            }
        }
        __syncthreads();
    }
    const int col = lane & 15, rq = (lane >> 4) * 4;
#pragma unroll
    for (int nb = 0; nb < 4; ++nb)
#pragma unroll
        for (int r = 0; r < 4; ++r) {
            int m = m0 + wave * 16 + rq + r, n = n0 + nb * 16 + col;
            if (n < N) atomicAdd(&Cacc[(size_t)m * N + n], acc[nb][r]);
        }
}

// epilogues: bias + leaky-relu -> bf16 (feeds next MFMA GEMM) / bias only -> fp32
__global__ void ep_lrelu_bf16(const float* __restrict__ acc, const float* __restrict__ bias,
                              __bf16* __restrict__ out, int M, int N) {
    int i = blockIdx.x * blockDim.x + threadIdx.x;
    if (i < M * N) {
        float v = acc[i] + bias[i % N];
        out[i] = (__bf16)(v > 0.f ? v : v * kSlope);
    }
}
__global__ void ep_bias_f32(const float* __restrict__ acc, const float* __restrict__ bias,
                            float* __restrict__ out, int M, int N) {
    int i = blockIdx.x * blockDim.x + threadIdx.x;
    if (i < M * N) out[i] = acc[i] + bias[i % N];
}

// ---------------------------------------------------------------------------
// xih via MFMA: xih[(s*B+b)*4H + n] = embb[q[b,s]] . w_ihb[n,:] + b_ih[n] + b_hh[n]
// A rows gathered via qs; w_ihb (4H x E) row-major == Bt layout. grid (80,16).
__global__ __launch_bounds__(256) void xih_mfma(
    const int* __restrict__ questions, const __bf16* __restrict__ embb,
    const __bf16* __restrict__ w_ihb, const float* __restrict__ b_ih,
    const float* __restrict__ b_hh, float* __restrict__ xih) {
    __shared__ __bf16 As[64][72];
    __shared__ __bf16 Bs[64][72];
    __shared__ int qs[64];
    const int m0 = blockIdx.x * 64, n0 = blockIdx.y * 64;
    const int tid = threadIdx.x, lane = tid & 63, wave = tid >> 6;
    if (tid < 64) {
        int m = m0 + tid;
        qs[tid] = questions[(m % kB) * kS + (m / kB)];
    }
    __syncthreads();
    floatx4 acc[4] = {};
    for (int k0 = 0; k0 < kE; k0 += 64) {
        for (int i = tid; i < 512; i += 256) {
            int r = i >> 3, seg = i & 7;
            *(uint4*)(&As[r][seg * 8]) =
                *(const uint4*)(embb + (size_t)qs[r] * kE + k0 + seg * 8);
        }
        for (int i = tid; i < 512; i += 256) {
            int r = i >> 3, seg = i & 7;
            *(uint4*)(&Bs[r][seg * 8]) =
                *(const uint4*)(w_ihb + (size_t)(n0 + r) * kE + k0 + seg * 8);
        }
        __syncthreads();
#pragma unroll
        for (int ks = 0; ks < 2; ++ks) {
            bf16x8 af = *(const bf16x8*)(&As[wave * 16 + (lane & 15)][ks * 32 + (lane >> 4) * 8]);
#pragma unroll
            for (int nb = 0; nb < 4; ++nb) {
                bf16x8 bfr = *(const bf16x8*)(&Bs[nb * 16 + (lane & 15)][ks * 32 + (lane >> 4) * 8]);
                acc[nb] = __builtin_amdgcn_mfma_f32_16x16x32_bf16(af, bfr, acc[nb], 0, 0, 0);
            }
        }
        __syncthreads();
    }
    const int col = lane & 15, rq = (lane >> 4) * 4;
#pragma unroll
    for (int nb = 0; nb < 4; ++nb)
#pragma unroll
        for (int r = 0; r < 4; ++r) {
            int m = m0 + wave * 16 + rq + r, n = n0 + nb * 16 + col;
            xih[(size_t)m * 1024 + n] = acc[nb][r] + b_ih[n] + b_hh[n];
        }
}

// ---------------------------------------------------------------------------
// One LSTM step: gates = xih_t + h_prev @ w_hh^T, then c/h update.
__global__ __launch_bounds__(256) void lstm_step(
    const float* __restrict__ xih_t, const float* __restrict__ w_hh,
    const float* __restrict__ h_prev, const float* __restrict__ c_prev,
    float* __restrict__ h_new, float* __restrict__ c_new) {
    __shared__ float As[32][33];
    __shared__ float Ws[4][32][33];
    const int b0 = blockIdx.x * 32, j0 = blockIdx.y * 32;
    const int tid = threadIdx.x, tj = tid % 16, tb = tid / 16;
    float acc[4][2][2] = {};
    for (int k0 = 0; k0 < kH; k0 += 32) {
        for (int i = tid; i < 32 * 32; i += 256) {
            int r = i / 32, c = i % 32;
            As[r][c] = h_prev[(size_t)(b0 + r) * kH + k0 + c];
        }
        for (int i = tid; i < 4 * 32 * 32; i += 256) {
            int g = i / 1024, rem = i % 1024, r = rem / 32, c = rem % 32;
            Ws[g][r][c] = w_hh[(size_t)(g * kH + j0 + r) * kH + k0 + c];
        }
        __syncthreads();
#pragma unroll
        for (int kk = 0; kk < 32; ++kk) {
            float a0 = As[tb * 2 + 0][kk], a1 = As[tb * 2 + 1][kk];
#pragma unroll
            for (int g = 0; g < 4; ++g) {
                float w0 = Ws[g][tj * 2 + 0][kk], w1 = Ws[g][tj * 2 + 1][kk];
                acc[g][0][0] += a0 * w0; acc[g][0][1] += a0 * w1;
                acc[g][1][0] += a1 * w0; acc[g][1][1] += a1 * w1;
            }
        }
        __syncthreads();
    }
#pragma unroll
    for (int bb = 0; bb < 2; ++bb)
#pragma unroll
        for (int jj = 0; jj < 2; ++jj) {
            int b = b0 + tb * 2 + bb, j = j0 + tj * 2 + jj;
            float gi = acc[0][bb][jj] + xih_t[(size_t)b * 1024 + 0 * kH + j];
            float gf = acc[1][bb][jj] + xih_t[(size_t)b * 1024 + 1 * kH + j];
            float gg = acc[2][bb][jj] + xih_t[(size_t)b * 1024 + 2 * kH + j];
            float go = acc[3][bb][jj] + xih_t[(size_t)b * 1024 + 3 * kH + j];
            float i_ = 1.f / (1.f + expf(-gi));
            float f_ = 1.f / (1.f + expf(-gf));
            float g_ = tanhf(gg);
            float o_ = 1.f / (1.f + expf(-go));
            float c = f_ * c_prev[(size_t)b * kH + j] + i_ * g_;
            c_new[(size_t)b * kH + j] = c;
            h_new[(size_t)b * kH + j] = o_ * tanhf(c);
        }
}

__global__ void bias_relu(const float* __restrict__ acc, const float* __restrict__ bias,
                          float* __restrict__ out, int M, int N) {
    int i = blockIdx.x * blockDim.x + threadIdx.x;
    if (i < M * N) {
        int n = i % N;
        out[i] = fmaxf(acc[i] + bias[n], 0.f);
    }
}

// ---------------------------------------------------------------------------
// MFMA tap-pair fused conv1(3->16) + conv2(16->16), 3x3, pad 1, no act between.
// One block = one sample x one 8-row output slab. Both convs use the SAME
// decomposition: K=32 MFMA covers tap-pair p (k<16 -> tap 2p, k>=16 -> tap 2p+1);
// A[o][k] holds the weights (zeros for c>=Cin or tap 9), B read from channel-
// contiguous LDS [row][col][ch16] (32B col stride, 16B-aligned b128 reads).
// Zero padding (image border AND conv2's padding of conv1 output) comes from
// the LDS memset: invalid rows are simply skipped.
constexpr int ICH = 16;   // img_s channel stride (bf16)
constexpr int MCH = 16;   // mid_s channel stride (bf16)

__global__ __launch_bounds__(256) void conv_fused_mfma(
    const float* __restrict__ img,     // (B,3,64,64)
    const float* __restrict__ all_w,   // (B,2768)
    __bf16* __restrict__ out) {        // (B,16,64,64) bf16
    const int b = blockIdx.y;
    const int y0 = blockIdx.x * 8;
    __shared__ __align__(16) __bf16 w1a[5 * 16 * 32];         // [pair][o][k]
    __shared__ __align__(16) __bf16 w2a[5 * 16 * 32];         // [pair][o][k]
    __shared__ float bias_s[32];                              // conv1 | conv2 bias
    __shared__ __align__(16) __bf16 img_s[12 * 66 * ICH];     // rows gy=y0-2..y0+9
    __shared__ __align__(16) __bf16 mid_s[10 * 66 * MCH];     // rows gy=y0-1..y0+8

    const int tid = threadIdx.x, lane = tid & 63, wave = tid >> 6;
    const float* wb = all_w + (size_t)b * kTotalW;

    // ---- phase A0: memset both LDS tiles (halo zeros + pad channels), weights ----
    for (int i = tid; i < 12 * 66 * ICH / 8; i += 256)
        ((uint4*)img_s)[i] = make_uint4(0u, 0u, 0u, 0u);
    for (int i = tid; i < 10 * 66 * MCH / 8; i += 256)
        ((uint4*)mid_s)[i] = make_uint4(0u, 0u, 0u, 0u);
    for (int i = tid; i < 2560; i += 256) {      // w1a: k=half*16+c, t=2p+half
        int p = i >> 9, rem = i & 511, o = rem >> 5, k = rem & 31;
        int half = k >> 4, c = k & 15, t = 2 * p + half;
        w1a[i] = (__bf16)((c < 3 && t < 9) ? wb[o * 27 + c * 9 + t] : 0.f);
    }
    for (int i = tid; i < 2560; i += 256) {      // w2a
        int p = i >> 9, rem = i & 511, o = rem >> 5, k = rem & 31;
        int half = k >> 4, c = k & 15, t = 2 * p + half;
        w2a[i] = (__bf16)((t < 9) ? wb[448 + (o * 16 + c) * 9 + t] : 0.f);
    }
    if (tid < 16) bias_s[tid] = wb[432 + tid];
    else if (tid < 32) bias_s[tid] = wb[2752 + (tid - 16)];
    __syncthreads();

    // ---- phase A1: fill real image pixels (coalesced global reads) ----
    for (int i = tid; i < 3 * 12 * 64; i += 256) {
        int c = i / 768, rem = i - c * 768, r = rem >> 6, x = rem & 63;
        int gy = y0 - 2 + r;
        if (gy >= 0 && gy < 64)
            img_s[(r * 66 + (x + 1)) * ICH + c] =
                (__bf16)img[(((size_t)b * 3 + c) << 12) + (gy << 6) + x];
    }
    __syncthreads();

    // per-lane fragment constants (shared by both convs)
    const int n = lane & 15, half = lane >> 5;
    const int c0 = ((lane >> 4) & 1) * 8, o0 = (lane >> 4) * 4;
    int dy_[5], dx_[5];
#pragma unroll
    for (int p = 0; p < 5; ++p) {
        int t = 2 * p + half;
        dy_[p] = (t < 9) ? t / 3 : 0;
        dx_[p] = (t < 9) ? t % 3 : 0;
    }
    bf16x8 a1[5], a2[5];
#pragma unroll
    for (int p = 0; p < 5; ++p) {
        a1[p] = *(const bf16x8*)&w1a[p * 512 + n * 32 + (lane >> 4) * 8];
        a2[p] = *(const bf16x8*)&w2a[p * 512 + n * 32 + (lane >> 4) * 8];
    }

    // ---- phase B: conv1, 40 tiles (10 mid-rows x 4 x-tiles), 10 per wave ----
#pragma unroll
    for (int ti = 0; ti < 10; ++ti) {
        int tile = wave * 10 + ti;
        int rr = tile >> 2, xt = (tile & 3) * 16;
        int gy = y0 - 1 + rr;                    // mid row's global y
        if (gy >= 0 && gy < 64) {                // else: stays zero (conv2's padding)
            floatx4 acc = {};
#pragma unroll
            for (int p = 0; p < 5; ++p) {
                bf16x8 bfr = *(const bf16x8*)
                    &img_s[((rr + dy_[p]) * 66 + (xt + n + dx_[p])) * ICH + c0];
                acc = __builtin_amdgcn_mfma_f32_16x16x32_bf16(a1[p], bfr, acc, 0, 0, 0);
            }
            union { short4 s4; __bf16 h[4]; } u;
#pragma unroll
            for (int q = 0; q < 4; ++q) u.h[q] = (__bf16)(acc[q] + bias_s[o0 + q]);
            *(short4*)&mid_s[(rr * 66 + (xt + n + 1)) * MCH + o0] = u.s4;
        }
    }
    __syncthreads();

    // ---- phase C: conv2, 32 tiles (8 rows x 4 x-tiles), 8 per wave ----
#pragma unroll
    for (int ti = 0; ti < 8; ++ti) {
        int tile = wave * 8 + ti;
        int rr = tile >> 2, xt = (tile & 3) * 16;
        floatx4 acc = {};
#pragma unroll
        for (int p = 0; p < 5; ++p) {
            bf16x8 bfr = *(const bf16x8*)
                &mid_s[((rr + dy_[p]) * 66 + (xt + n + dx_[p])) * MCH + c0];
            acc = __builtin_amdgcn_mfma_f32_16x16x32_bf16(a2[p], bfr, acc, 0, 0, 0);
        }
        int gy = y0 + rr, gx = xt + n;
#pragma unroll
        for (int q = 0; q < 4; ++q)
            out[(((size_t)b * 16 + o0 + q) * 64 + gy) * 64 + gx] =
                (__bf16)(acc[q] + bias_s[16 + o0 + q]);
    }
}

// ---------------------------------------------------------------------------
// Fused lin2+lin3: out(256,2). grid B, block 64.
__global__ __launch_bounds__(64) void lin23(
    const float* __restrict__ l1out,
    const float* __restrict__ lw2, const float* __restrict__ lb2,
    const float* __restrict__ lw3, const float* __restrict__ lb3,
    float* __restrict__ out) {
    const int b = blockIdx.x, j = threadIdx.x;
    __shared__ float row[512];
    __shared__ float s[64];
    for (int i = j; i < 512; i += 64) row[i] = l1out[(size_t)b * 512 + i];
    __syncthreads();
    float acc = lb2[j];
    for (int k = 0; k < 512; ++k) acc += row[k] * lw2[(size_t)k * 64 + j];
    s[j] = fmaxf(acc, 0.f);
    __syncthreads();
    if (j < 2) {
        float o = lb3[j];
        for (int k = 0; k < 64; ++k) o += s[k] * lw3[(size_t)k * 2 + j];
        out[(size_t)b * 2 + j] = o;
    }
}

// ---------------------------------------------------------------------------
extern "C" void kernel_launch(void* const* d_in, const int* in_sizes, int n_in,
                              void* d_out, int out_size, void* d_ws, size_t ws_size,
                              hipStream_t stream) {
    const int* questions = (const int*)d_in[0];
    const float* images  = (const float*)d_in[1];
    const float* emb     = (const float*)d_in[2];
    const float* w_ih    = (const float*)d_in[3];
    const float* w_hh    = (const float*)d_in[4];
    const float* b_ih    = (const float*)d_in[5];
    const float* b_hh    = (const float*)d_in[6];
    const float* hw1     = (const float*)d_in[7];
    const float* hb1     = (const float*)d_in[8];
    const float* hw2     = (const float*)d_in[9];
    const float* hb2     = (const float*)d_in[10];
    const float* hw3     = (const float*)d_in[11];
    const float* hb3     = (const float*)d_in[12];
    const float* lw1     = (const float*)d_in[13];
    const float* lb1     = (const float*)d_in[14];
    const float* lw2     = (const float*)d_in[15];
    const float* lb2     = (const float*)d_in[16];
    const float* lw3     = (const float*)d_in[17];
    const float* lb3     = (const float*)d_in[18];
    float* out = (float*)d_out;

    char* ws = (char*)d_ws;
    size_t off = 0;
    auto alloc = [&](size_t nbytes) -> void* {
        void* p = (void*)(ws + off);
        off += (nbytes + 255) & ~(size_t)255;
        return p;
    };
    // big (64MB) timeline (single stream, strictly ordered):
    //   [0..20MB)  xih fp32            (dead after LSTM)
    //   [24..47MB) w3t bf16            (dead after hw3 MFMA GEMM)
    //   [0..32MB)  conv out bf16       (written by conv_fused_mfma, after both above dead)
    float*  big   = (float*)alloc(64ull << 20);
    __bf16* lw1t  = (__bf16*)alloc((size_t)512 * 65536 * 2);   // lw1^T bf16
    float*  hc0   = (float*)alloc(2 * kB * kH * sizeof(float));
    float*  hc1   = (float*)alloc(2 * kB * kH * sizeof(float));
    __bf16* w1t   = (__bf16*)alloc((size_t)1024 * 256 * 2);    // hw1^T bf16
    __bf16* w2t   = (__bf16*)alloc((size_t)4096 * 1024 * 2);   // hw2^T bf16
    __bf16* embb  = (__bf16*)alloc((size_t)10000 * kE * 2);    // emb bf16
    __bf16* w_ihb = (__bf16*)alloc((size_t)1024 * kE * 2);     // w_ih bf16 (already (N,K))
    __bf16* h0b   = (__bf16*)alloc((size_t)kB * kH * 2);
    __bf16* h1b   = (__bf16*)alloc((size_t)kB * 1024 * 2);
    __bf16* h2b   = (__bf16*)alloc((size_t)kB * 4096 * 2);
    // contiguous fp32 accumulators (zeroed in one kernel): hw1 | hw2 | hw3 | lin1
    float*  accz  = (float*)alloc((size_t)kB * (1024 + 4096 + 2768 + 512) * sizeof(float));
    float*  accA  = accz;
    float*  accB  = accA + (size_t)kB * 1024;
    float*  accC  = accB + (size_t)kB * 4096;
    float*  acc1  = accC + (size_t)kB * 2768;
    float*  allw  = (float*)alloc((size_t)kB * kTotalW * sizeof(float));
    float*  l1out = (float*)alloc((size_t)kB * 512 * sizeof(float));

    float*  xih    = big;
    __bf16* c2out  = (__bf16*)big;
    __bf16* w3t    = (__bf16*)((char*)big + (24ull << 20));    // 2768 x 4096 bf16
    float* hbuf[2] = {hc0, hc1};
    float* cbuf[2] = {hc0 + kB * kH, hc1 + kB * kH};

    const int nACC = kB * (1024 + 4096 + 2768 + 512);
    zero_f32<<<512, 256, 0, stream>>>(accz, nACC);
    zero_f32<<<256, 256, 0, stream>>>(hc0, 2 * kB * kH);       // h0=c0=0

    // weight converts/transposes (regions disjoint from their concurrent readers/writers)
    cvt_bf16<<<1280, 256, 0, stream>>>(emb, embb, 10000 * kE);
    cvt_bf16<<<128, 256, 0, stream>>>(w_ih, w_ihb, 1024 * kE);
    transpose_cvt<<<dim3(8, 32),   256, 0, stream>>>(hw1, w1t, 256, 1024);
    transpose_cvt<<<dim3(32, 128), 256, 0, stream>>>(hw2, w2t, 1024, 4096);
    transpose_cvt<<<dim3(128, 87), 256, 0, stream>>>(hw3, w3t, 4096, 2768);
    transpose_cvt<<<dim3(2048, 16), 256, 0, stream>>>(lw1, lw1t, 65536, 512);

    // 1) xih = emb[q] @ w_ih^T + b_ih + b_hh via MFMA, laid out (S,B,4H)
    xih_mfma<<<dim3(80, 16), 256, 0, stream>>>(questions, embb, w_ihb, b_ih, b_hh, xih);

    // 2) 20 LSTM steps (ping-pong h/c)
    for (int t = 0; t < kS; ++t) {
        lstm_step<<<dim3(8, 8), 256, 0, stream>>>(
            xih + (size_t)t * kB * 1024, w_hh,
            hbuf[t & 1], cbuf[t & 1], hbuf[(t + 1) & 1], cbuf[(t + 1) & 1]);
    }
    const float* hfin = hbuf[0];  // t=19 writes buffer 0
    cvt_bf16<<<64, 256, 0, stream>>>(hfin, h0b, kB * kH);

    // 3) hyper-MLP via bf16 MFMA split-K GEMMs
    mfma_splitk<<<dim3(4, 16, 4), 256, 0, stream>>>(h0b, w1t, accA, 256, 1024, 256, 64);
    ep_lrelu_bf16<<<1024, 256, 0, stream>>>(accA, hb1, h1b, 256, 1024);
    mfma_splitk<<<dim3(4, 64, 4), 256, 0, stream>>>(h1b, w2t, accB, 256, 4096, 1024, 256);
    ep_lrelu_bf16<<<4096, 256, 0, stream>>>(accB, hb2, h2b, 256, 4096);
    mfma_splitk<<<dim3(4, 44, 8), 256, 0, stream>>>(h2b, w3t, accC, 256, 2768, 4096, 512);
    ep_bias_f32<<<2768, 256, 0, stream>>>(accC, hb3, allw, 256, 2768);

    // 4) fused conv1+conv2 via MFMA tap-pair implicit GEMM -> bf16
    conv_fused_mfma<<<dim3(8, 256), 256, 0, stream>>>(images, allw, c2out);

    // 5) lin1 via bf16 MFMA split-K: 256x512, K=65536, splits=32
    mfma_splitk<<<dim3(4, 8, 32), 256, 0, stream>>>(c2out, lw1t, acc1, 256, 512, 65536, 2048);
    bias_relu<<<512, 256, 0, stream>>>(acc1, lb1, l1out, 256, 512);

    // 6) lin2+lin3 fused -> out (256,2)
    lin23<<<256, 64, 0, stream>>>(l1out, lw2, lb2, lw3, lb3, out);
}